// Round 11
// baseline (485.559 us; speedup 1.0000x reference)
//
#include <hip/hip_runtime.h>
#include <math.h>

typedef _Float16 half8 __attribute__((ext_vector_type(8)));
typedef float floatx4 __attribute__((ext_vector_type(4)));

#define NROWS 131072
#define BM1 128
#define W1S_BYTES (32 * 32768)
#define H_BYTES ((size_t)NROWS * 256 * 4)

// ---- gemm1 / fused LDS map (96 KiB): double-buffered A and B (r6 layout) ----
#define A0b 0
#define A1b 16384
#define B0b 32768
#define B1b 65536
// ---- phase-2 map: H: [32][512B] per plane (XOR-swizzled); P: [32][64] f32
#define H_H 0
#define H_L 16384
#define P_F 32768

#define TAU 1e-4f

// Counted-vmcnt barriers (T4): drain glds (older) but keep the 2 newest A
// prefetch loads in flight across the barrier. lgkmcnt(0) publishes ds_writes.
// Release fence (memory clobber) before s_barrier, acquire fence after.
#define BAR_KEEP2() do {                                                     \
    asm volatile("s_waitcnt vmcnt(2) lgkmcnt(0)" ::: "memory");              \
    __builtin_amdgcn_s_barrier();                                            \
    asm volatile("" ::: "memory");                                           \
  } while (0)
#define BAR_DRAIN() do {                                                     \
    asm volatile("s_waitcnt vmcnt(0) lgkmcnt(0)" ::: "memory");              \
    __builtin_amdgcn_s_barrier();                                            \
    asm volatile("" ::: "memory");                                           \
  } while (0)

__device__ __forceinline__ float gelu_exact(float z) {
  return 0.5f * z * (1.0f + erff(z * 0.70710678118654752f));
}

// Pre-split W1 (scale 64) into per-k-tile images laid out byte-identically to
// the LDS B-tile; also zeroes the tie-list counter.
__global__ __launch_bounds__(256) void router_prep(const float* __restrict__ W1,
                                                   unsigned char* __restrict__ w1s,
                                                   int* __restrict__ cnt) {
  if (blockIdx.x == 0 && threadIdx.x == 0) *cnt = 0;
  int p = blockIdx.x * 256 + threadIdx.x;
  int col = p & 255;
  int g   = (p >> 8) & 3;
  int kt  = p >> 10;
  half8 hh, hl;
#pragma unroll
  for (int e = 0; e < 8; ++e) {
    float v = W1[(size_t)(kt * 32 + g * 8 + e) * 256 + col] * 64.0f;
    _Float16 h = (_Float16)v;
    hh[e] = h;
    hl[e] = (_Float16)(v - (float)h);
  }
  int off = col * 64 + ((g + (col >> 1)) & 3) * 16;
  unsigned char* base = w1s + (size_t)kt * 32768;
  *(half8*)(base + off) = hh;
  *(half8*)(base + 16384 + off) = hl;
}

// B tile via global_load_lds: image byte-identical to LDS layout, lane-consecutive.
#define GLDS_B(KT, BB) do {                                                  \
    const unsigned char* gp_ = w1s + (size_t)(KT) * 32768 + tid * 16;        \
    _Pragma("unroll") for (int j_ = 0; j_ < 4; ++j_) {                       \
      __builtin_amdgcn_global_load_lds(                                      \
        (const __attribute__((address_space(1))) void*)(gp_ + j_ * 8192),    \
        (__attribute__((address_space(3))) void*)(smem + (BB) + (w << 10) + j_ * 8192), \
        16, 0, 0);                                                           \
    }                                                                        \
  } while (0)

#define LOAD_A(KT, A0, A1) do {                                              \
    const float* ap_ = aptr + (KT) * 32;                                     \
    A0 = *(const float4*)(ap_);                                              \
    A1 = *(const float4*)(ap_ + 4);                                          \
  } while (0)

#define STAGE_A(A0, A1, AB) do {                                             \
    float av_[8] = {A0.x, A0.y, A0.z, A0.w, A1.x, A1.y, A1.z, A1.w};         \
    half8 hh_, hl_;                                                          \
    _Pragma("unroll") for (int e_ = 0; e_ < 8; ++e_) {                       \
      float x_ = av_[e_] * 16.0f;                                            \
      _Float16 h_ = (_Float16)x_;                                            \
      hh_[e_] = h_;                                                          \
      hl_[e_] = (_Float16)(x_ - (float)h_);                                  \
    }                                                                        \
    *(half8*)(smem + (AB) + awo)        = hh_;                               \
    *(half8*)(smem + (AB) + awo + 8192) = hl_;                               \
  } while (0)

#define MFMA_STEP(AB, BB) do {                                               \
    half8 bfh_[4], bfl_[4];                                                  \
    _Pragma("unroll") for (int nf_ = 0; nf_ < 4; ++nf_) {                    \
      int c_ = wc * 64 + nf_ * 16 + lr;                                      \
      int off_ = c_ * 64 + ((lg + (c_ >> 1)) & 3) * 16;                      \
      bfh_[nf_] = *(half8*)(smem + (BB) + off_);                             \
      bfl_[nf_] = *(half8*)(smem + (BB) + 16384 + off_);                     \
    }                                                                        \
    _Pragma("unroll") for (int mf_ = 0; mf_ < 4; ++mf_) {                    \
      int r_ = wr * 64 + mf_ * 16 + lr;                                      \
      int off_ = r_ * 64 + ((lg + (r_ >> 1)) & 3) * 16;                      \
      half8 ah_  = *(half8*)(smem + (AB) + off_);                            \
      half8 al_  = *(half8*)(smem + (AB) + 8192 + off_);                     \
      _Pragma("unroll") for (int nf_ = 0; nf_ < 4; ++nf_) {                  \
        acc[mf_][nf_] = __builtin_amdgcn_mfma_f32_16x16x32_f16(ah_, bfh_[nf_], acc[mf_][nf_], 0, 0, 0); \
        acc[mf_][nf_] = __builtin_amdgcn_mfma_f32_16x16x32_f16(ah_, bfl_[nf_], acc[mf_][nf_], 0, 0, 0); \
        acc[mf_][nf_] = __builtin_amdgcn_mfma_f32_16x16x32_f16(al_, bfh_[nf_], acc[mf_][nf_], 0, 0, 0); \
      }                                                                      \
    }                                                                        \
  } while (0)

// ================= GEMM1: h = gelu(feat @ W1 + b1) -> ws (f32), BM1=128 ====
// r9 structure with counted-vmcnt barriers: glds drained at each barrier
// (cross-wave publish), the 2 newest A HBM loads stay in flight.
__global__ __launch_bounds__(512, 2) void router_gemm1(
    const float* __restrict__ feat, const unsigned char* __restrict__ w1s,
    const float* __restrict__ b1, float* __restrict__ hbuf)
{
  __shared__ __align__(16) unsigned char smem[98304];
  const int tid = threadIdx.x;
  const int w  = tid >> 6;
  const int l  = tid & 63;
  const int lr = l & 15;
  const int lg = l >> 4;
  const int wr = w >> 2;
  const int wc = w & 3;
  const int row0 = blockIdx.x * BM1;

  floatx4 acc[4][4];
  const floatx4 z4 = {0.f, 0.f, 0.f, 0.f};
#pragma unroll
  for (int m = 0; m < 4; ++m)
#pragma unroll
    for (int n = 0; n < 4; ++n) acc[m][n] = z4;

  const int arow = tid >> 2;
  const int aq   = tid & 3;
  const float* aptr = feat + (size_t)(row0 + arow) * 1024 + aq * 8;
  const int awo = arow * 64 + ((aq + (arow >> 1)) & 3) * 16;

  float4 aE0, aE1, aO0, aO1;

  // prologue: glds(B0) oldest, then E, O loads. STAGE_A(E) forces vmcnt(2)
  // (keeps O) which also retires B0 glds -> barrier can keep O in flight.
  GLDS_B(0, B0b);
  LOAD_A(0, aE0, aE1);
  LOAD_A(1, aO0, aO1);
  STAGE_A(aE0, aE1, A0b);
  BAR_KEEP2();

#pragma unroll 1
  for (int kt = 0; kt < 32; kt += 2) {
    // half 1: consume A0/B0; publish A1 (+B1 glds in flight until barrier)
    GLDS_B(kt + 1, B1b);
    if (kt + 2 < 32) LOAD_A(kt + 2, aE0, aE1);
    STAGE_A(aO0, aO1, A1b);
    MFMA_STEP(A0b, B0b);
    if (kt + 2 < 32) BAR_KEEP2(); else BAR_DRAIN();
    // half 2: consume A1/B1; publish A0 (+B0 glds)
    if (kt + 2 < 32) {
      GLDS_B(kt + 2, B0b);
      STAGE_A(aE0, aE1, A0b);
    }
    if (kt + 3 < 32) LOAD_A(kt + 3, aO0, aO1);
    MFMA_STEP(A1b, B1b);
    if (kt + 3 < 32) BAR_KEEP2(); else BAR_DRAIN();
  }

  // epilogue: h = gelu(z) -> global f32 (exact; same values as fused path)
  float b1v[4];
#pragma unroll
  for (int n = 0; n < 4; ++n) b1v[n] = b1[wc * 64 + n * 16 + lr];
#pragma unroll
  for (int m = 0; m < 4; ++m)
#pragma unroll
    for (int nf = 0; nf < 4; ++nf)
#pragma unroll
      for (int q = 0; q < 4; ++q) {
        float z = acc[m][nf][q] * (1.0f / 1024.0f) + b1v[nf];
        float hv = gelu_exact(z);
        int r = wr * 64 + m * 16 + lg * 4 + q;
        int c = wc * 64 + nf * 16 + lr;
        hbuf[(size_t)(row0 + r) * 256 + c] = hv;
      }
}

// ================= GEMM2: logits/softmax/topk from h (unchanged from r9) ===
__global__ __launch_bounds__(512, 4) void router_gemm2(
    const float* __restrict__ hbuf, const float* __restrict__ W2,
    const float* __restrict__ b2, float* __restrict__ out,
    int* __restrict__ cnt, int* __restrict__ list, int cap)
{
  __shared__ __align__(16) unsigned char smem[40960];
  const int tid = threadIdx.x;
  const int w  = tid >> 6;
  const int l  = tid & 63;
  const int lr = l & 15;
  const int lg = l >> 4;
  const int wr = w >> 2;     // k half
  const int wc = w & 3;      // col frag
  const int row0 = blockIdx.x * 32;
  const floatx4 z4 = {0.f, 0.f, 0.f, 0.f};

  half8 w2h[4], w2l[4];
#pragma unroll
  for (int ks = 0; ks < 4; ++ks)
#pragma unroll
    for (int jj = 0; jj < 8; ++jj) {
      int j = wr * 128 + ks * 32 + lg * 8 + jj;
      float v = W2[(size_t)j * 64 + wc * 16 + lr] * 64.0f;
      _Float16 h = (_Float16)v;
      w2h[ks][jj] = h;
      w2l[ks][jj] = (_Float16)(v - (float)h);
    }
  const int s_ep = tid & 15;
  const int r_ep = tid >> 4;   // 0..31
  float b2v[4];
#pragma unroll
  for (int n = 0; n < 4; ++n) b2v[n] = b2[s_ep + 16 * n];

  // stage h rows (scale 32, split f16) into XOR-swizzled LDS
  {
    const int hr  = tid >> 4;         // 0..31
    const int hc0 = (tid & 15) * 16;  // 16 cols per thread
    const float* hp = hbuf + (size_t)(row0 + hr) * 256 + hc0;
    float4 hv0 = *(const float4*)(hp);
    float4 hv1 = *(const float4*)(hp + 4);
    float4 hv2 = *(const float4*)(hp + 8);
    float4 hv3 = *(const float4*)(hp + 12);
    float hvs[16] = {hv0.x, hv0.y, hv0.z, hv0.w, hv1.x, hv1.y, hv1.z, hv1.w,
                     hv2.x, hv2.y, hv2.z, hv2.w, hv3.x, hv3.y, hv3.z, hv3.w};
#pragma unroll
    for (int j = 0; j < 16; ++j) {
      float hs = hvs[j] * 32.0f;
      _Float16 hi = (_Float16)hs;
      _Float16 lo = (_Float16)(hs - (float)hi);
      int cj = hc0 + j;
      int off = hr * 512 + (((cj >> 3) ^ (hr & 7)) * 16) + (cj & 7) * 2;
      *(_Float16*)(smem + H_H + off) = hi;
      *(_Float16*)(smem + H_L + off) = lo;
    }
  }
  __syncthreads();

  floatx4 acc2[2] = {z4, z4};
#pragma unroll
  for (int mf = 0; mf < 2; ++mf) {
    int rl = mf * 16 + lr;
#pragma unroll
    for (int ks = 0; ks < 4; ++ks) {
      int g = wr * 16 + ks * 4 + lg;
      int off = rl * 512 + ((g ^ (rl & 7)) * 16);
      half8 ha = *(half8*)(smem + H_H + off);
      half8 la = *(half8*)(smem + H_L + off);
      acc2[mf] = __builtin_amdgcn_mfma_f32_16x16x32_f16(ha, w2h[ks], acc2[mf], 0, 0, 0);
      acc2[mf] = __builtin_amdgcn_mfma_f32_16x16x32_f16(ha, w2l[ks], acc2[mf], 0, 0, 0);
      acc2[mf] = __builtin_amdgcn_mfma_f32_16x16x32_f16(la, w2h[ks], acc2[mf], 0, 0, 0);
    }
  }
  if (w >= 4) {
#pragma unroll
    for (int mf = 0; mf < 2; ++mf)
#pragma unroll
      for (int q = 0; q < 4; ++q) {
        int rp = mf * 16 + lg * 4 + q;
        int cp = wc * 16 + lr;
        *(float*)(smem + P_F + (rp * 64 + cp) * 4) = acc2[mf][q];
      }
  }
  __syncthreads();
  if (w < 4) {
#pragma unroll
    for (int mf = 0; mf < 2; ++mf)
#pragma unroll
      for (int q = 0; q < 4; ++q) {
        int rp = mf * 16 + lg * 4 + q;
        int cp = wc * 16 + lr;
        float* p = (float*)(smem + P_F + (rp * 64 + cp) * 4);
        *p = *p + acc2[mf][q];
      }
  }
  __syncthreads();

  float* outU = out;
  float* outI = out + (size_t)NROWS * 64;
  float* outS = out + (size_t)NROWS * 64 + (size_t)NROWS * 3;

  {
    int rowg = row0 + r_ep;
    float vals[4];
#pragma unroll
    for (int n = 0; n < 4; ++n)
      vals[n] = (*(float*)(smem + P_F + (r_ep * 64 + s_ep + 16 * n) * 4)) * (1.0f / 2048.0f) + b2v[n];

    float m1 = fmaxf(fmaxf(vals[0], vals[1]), fmaxf(vals[2], vals[3]));
#pragma unroll
    for (int d = 1; d < 16; d <<= 1) m1 = fmaxf(m1, __shfl_xor(m1, d));
    float e[4], ss = 0.f;
#pragma unroll
    for (int n = 0; n < 4; ++n) { e[n] = __expf(vals[n] - m1); ss += e[n]; }
#pragma unroll
    for (int d = 1; d < 16; d <<= 1) ss += __shfl_xor(ss, d);
    float inv = 1.0f / ss;
    float ps[4];
#pragma unroll
    for (int n = 0; n < 4; ++n) {
      ps[n] = e[n] * inv;
      outS[(size_t)rowg * 64 + s_ep + 16 * n] = ps[n];
    }
    float cur[4] = {vals[0], vals[1], vals[2], vals[3]};
    float tv[4]; int tc[4];
#pragma unroll
    for (int t = 0; t < 4; ++t) {
      float bv = -3.0e38f; int bc = 1 << 20;
#pragma unroll
      for (int n = 0; n < 4; ++n)
        if (cur[n] > bv) { bv = cur[n]; bc = s_ep + 16 * n; }
#pragma unroll
      for (int d = 1; d < 16; d <<= 1) {
        float ov = __shfl_xor(bv, d);
        int  oc = __shfl_xor(bc, d);
        if (ov > bv || (ov == bv && oc < bc)) { bv = ov; bc = oc; }
      }
      tv[t] = bv; tc[t] = bc;
#pragma unroll
      for (int n = 0; n < 4; ++n) if (s_ep + 16 * n == bc) cur[n] = -3.0e38f;
    }
    float l2[4];
#pragma unroll
    for (int n = 0; n < 4; ++n) {
      float p = fmaxf(ps[n], 1e-12f);
      float p2 = p * p;
      float p4 = p2 * p2;
      float lgv = logf(p4 + 1e-12f);
      int c = s_ep + 16 * n;
      bool top = (c == tc[0]) | (c == tc[1]) | (c == tc[2]);
      l2[n] = 10.0f * lgv + (top ? 0.0f : -46.051701859880914f);
    }
    float m2 = fmaxf(fmaxf(l2[0], l2[1]), fmaxf(l2[2], l2[3]));
#pragma unroll
    for (int d = 1; d < 16; d <<= 1) m2 = fmaxf(m2, __shfl_xor(m2, d));
    float e2[4], s2 = 0.f;
#pragma unroll
    for (int n = 0; n < 4; ++n) { e2[n] = __expf(l2[n] - m2); s2 += e2[n]; }
#pragma unroll
    for (int d = 1; d < 16; d <<= 1) s2 += __shfl_xor(s2, d);
    float inv2 = 1.0f / s2;
#pragma unroll
    for (int n = 0; n < 4; ++n) outU[(size_t)rowg * 64 + s_ep + 16 * n] = e2[n] * inv2;

    if (s_ep == 0) {
      outI[(size_t)rowg * 3 + 0] = (float)tc[0];
      outI[(size_t)rowg * 3 + 1] = (float)tc[1];
      outI[(size_t)rowg * 3 + 2] = (float)tc[2];
      float mg = fminf(tv[0] - tv[1], fminf(tv[1] - tv[2], tv[2] - tv[3]));
      if (mg < TAU && cap > 0) {
        int pos = atomicAdd(cnt, 1);
        if (pos < cap) list[pos] = rowg;
      }
    }
  }
}

// ================= fused fallback (r6 winner, BM=128, __syncthreads) =======
__global__ __launch_bounds__(512, 2) void router_fused(
    const float* __restrict__ feat, const unsigned char* __restrict__ w1s,
    const float* __restrict__ b1, const float* __restrict__ W2,
    const float* __restrict__ b2, float* __restrict__ out,
    int* __restrict__ cnt, int* __restrict__ list, int cap)
{
  __shared__ __align__(16) unsigned char smem[98304];
  const int tid = threadIdx.x;
  const int w  = tid >> 6;
  const int l  = tid & 63;
  const int lr = l & 15;
  const int lg = l >> 4;
  const int wr = w >> 2;
  const int wc = w & 3;
  const int row0 = blockIdx.x * 128;

  floatx4 acc[4][4];
  const floatx4 z4 = {0.f, 0.f, 0.f, 0.f};
#pragma unroll
  for (int m = 0; m < 4; ++m)
#pragma unroll
    for (int n = 0; n < 4; ++n) acc[m][n] = z4;

  const int arow = tid >> 2;
  const int aq   = tid & 3;
  const float* aptr = feat + (size_t)(row0 + arow) * 1024 + aq * 8;
  const int awo = arow * 64 + ((aq + (arow >> 1)) & 3) * 16;

  float4 aE0, aE1, aO0, aO1;

  GLDS_B(0, B0b);
  LOAD_A(0, aE0, aE1);
  LOAD_A(1, aO0, aO1);
  STAGE_A(aE0, aE1, A0b);
  __syncthreads();

#pragma unroll 1
  for (int kt = 0; kt < 32; kt += 2) {
    GLDS_B(kt + 1, B1b);
    if (kt + 2 < 32) LOAD_A(kt + 2, aE0, aE1);
    STAGE_A(aO0, aO1, A1b);
    MFMA_STEP(A0b, B0b);
    __syncthreads();
    if (kt + 2 < 32) {
      GLDS_B(kt + 2, B0b);
      STAGE_A(aE0, aE1, A0b);
    }
    if (kt + 3 < 32) LOAD_A(kt + 3, aO0, aO1);
    MFMA_STEP(A1b, B1b);
    __syncthreads();
  }

  half8 w2h[4], w2l[4];
#pragma unroll
  for (int ks = 0; ks < 4; ++ks)
#pragma unroll
    for (int jj = 0; jj < 8; ++jj) {
      int j = wr * 128 + ks * 32 + lg * 8 + jj;
      float v = W2[(size_t)j * 64 + wc * 16 + lr] * 64.0f;
      _Float16 h = (_Float16)v;
      w2h[ks][jj] = h;
      w2l[ks][jj] = (_Float16)(v - (float)h);
    }
  float b1v[4];
#pragma unroll
  for (int n = 0; n < 4; ++n) b1v[n] = b1[wc * 64 + n * 16 + lr];
  const int s_ep = tid & 15;
  const int r_ep = tid >> 4;
  float b2v[4];
#pragma unroll
  for (int n = 0; n < 4; ++n) b2v[n] = b2[s_ep + 16 * n];

  float* outU = out;
  float* outI = out + (size_t)NROWS * 64;
  float* outS = out + (size_t)NROWS * 64 + (size_t)NROWS * 3;

#pragma unroll
  for (int ch = 0; ch < 4; ++ch) {
    if (wr == (ch >> 1)) {
#pragma unroll
      for (int mm = 0; mm < 2; ++mm) {
        const int m = (ch & 1) * 2 + mm;
#pragma unroll
        for (int nf = 0; nf < 4; ++nf) {
#pragma unroll
          for (int q = 0; q < 4; ++q) {
            float z = acc[m][nf][q] * (1.0f / 1024.0f) + b1v[nf];
            float hs = gelu_exact(z) * 32.0f;
            _Float16 hi = (_Float16)hs;
            _Float16 lo = (_Float16)(hs - (float)hi);
            int rl = mm * 16 + lg * 4 + q;
            int cj = wc * 64 + nf * 16 + lr;
            int off = rl * 512 + (((cj >> 3) ^ (rl & 7)) * 16) + (cj & 7) * 2;
            *(_Float16*)(smem + H_H + off) = hi;
            *(_Float16*)(smem + H_L + off) = lo;
          }
        }
      }
    }
    __syncthreads();
    floatx4 acc2[2] = {z4, z4};
#pragma unroll
    for (int mf = 0; mf < 2; ++mf) {
      int rl = mf * 16 + lr;
#pragma unroll
      for (int ks = 0; ks < 4; ++ks) {
        int g = wr * 16 + ks * 4 + lg;
        int off = rl * 512 + ((g ^ (rl & 7)) * 16);
        half8 ha = *(half8*)(smem + H_H + off);
        half8 la = *(half8*)(smem + H_L + off);
        acc2[mf] = __builtin_amdgcn_mfma_f32_16x16x32_f16(ha, w2h[ks], acc2[mf], 0, 0, 0);
        acc2[mf] = __builtin_amdgcn_mfma_f32_16x16x32_f16(ha, w2l[ks], acc2[mf], 0, 0, 0);
        acc2[mf] = __builtin_amdgcn_mfma_f32_16x16x32_f16(la, w2h[ks], acc2[mf], 0, 0, 0);
      }
    }
    if (w >= 4) {
#pragma unroll
      for (int mf = 0; mf < 2; ++mf)
#pragma unroll
        for (int q = 0; q < 4; ++q) {
          int rp = mf * 16 + lg * 4 + q;
          int cp = wc * 16 + lr;
          *(float*)(smem + P_F + (rp * 64 + cp) * 4) = acc2[mf][q];
        }
    }
    __syncthreads();
    if (w < 4) {
#pragma unroll
      for (int mf = 0; mf < 2; ++mf)
#pragma unroll
        for (int q = 0; q < 4; ++q) {
          int rp = mf * 16 + lg * 4 + q;
          int cp = wc * 16 + lr;
          float* p = (float*)(smem + P_F + (rp * 64 + cp) * 4);
          *p = *p + acc2[mf][q];
        }
    }
    __syncthreads();
    {
      int rowg = row0 + ch * 32 + r_ep;
      float vals[4];
#pragma unroll
      for (int n = 0; n < 4; ++n)
        vals[n] = (*(float*)(smem + P_F + (r_ep * 64 + s_ep + 16 * n) * 4)) * (1.0f / 2048.0f) + b2v[n];

      float m1 = fmaxf(fmaxf(vals[0], vals[1]), fmaxf(vals[2], vals[3]));
#pragma unroll
      for (int d = 1; d < 16; d <<= 1) m1 = fmaxf(m1, __shfl_xor(m1, d));
      float e[4], ss = 0.f;
#pragma unroll
      for (int n = 0; n < 4; ++n) { e[n] = __expf(vals[n] - m1); ss += e[n]; }
#pragma unroll
      for (int d = 1; d < 16; d <<= 1) ss += __shfl_xor(ss, d);
      float inv = 1.0f / ss;
      float ps[4];
#pragma unroll
      for (int n = 0; n < 4; ++n) {
        ps[n] = e[n] * inv;
        outS[(size_t)rowg * 64 + s_ep + 16 * n] = ps[n];
      }
      float cur[4] = {vals[0], vals[1], vals[2], vals[3]};
      float tv[4]; int tc[4];
#pragma unroll
      for (int t = 0; t < 4; ++t) {
        float bv = -3.0e38f; int bc = 1 << 20;
#pragma unroll
        for (int n = 0; n < 4; ++n)
          if (cur[n] > bv) { bv = cur[n]; bc = s_ep + 16 * n; }
#pragma unroll
        for (int d = 1; d < 16; d <<= 1) {
          float ov = __shfl_xor(bv, d);
          int  oc = __shfl_xor(bc, d);
          if (ov > bv || (ov == bv && oc < bc)) { bv = ov; bc = oc; }
        }
        tv[t] = bv; tc[t] = bc;
#pragma unroll
        for (int n = 0; n < 4; ++n) if (s_ep + 16 * n == bc) cur[n] = -3.0e38f;
      }
      float l2[4];
#pragma unroll
      for (int n = 0; n < 4; ++n) {
        float p = fmaxf(ps[n], 1e-12f);
        float p2 = p * p;
        float p4 = p2 * p2;
        float lgv = logf(p4 + 1e-12f);
        int c = s_ep + 16 * n;
        bool top = (c == tc[0]) | (c == tc[1]) | (c == tc[2]);
        l2[n] = 10.0f * lgv + (top ? 0.0f : -46.051701859880914f);
      }
      float m2 = fmaxf(fmaxf(l2[0], l2[1]), fmaxf(l2[2], l2[3]));
#pragma unroll
      for (int d = 1; d < 16; d <<= 1) m2 = fmaxf(m2, __shfl_xor(m2, d));
      float e2[4], s2 = 0.f;
#pragma unroll
      for (int n = 0; n < 4; ++n) { e2[n] = __expf(l2[n] - m2); s2 += e2[n]; }
#pragma unroll
      for (int d = 1; d < 16; d <<= 1) s2 += __shfl_xor(s2, d);
      float inv2 = 1.0f / s2;
#pragma unroll
      for (int n = 0; n < 4; ++n) outU[(size_t)rowg * 64 + s_ep + 16 * n] = e2[n] * inv2;

      if (s_ep == 0) {
        outI[(size_t)rowg * 3 + 0] = (float)tc[0];
        outI[(size_t)rowg * 3 + 1] = (float)tc[1];
        outI[(size_t)rowg * 3 + 2] = (float)tc[2];
        float mg = fminf(tv[0] - tv[1], fminf(tv[1] - tv[2], tv[2] - tv[3]));
        if (mg < TAU && cap > 0) {
          int pos = atomicAdd(cnt, 1);
          if (pos < cap) list[pos] = rowg;
        }
      }
    }
    __syncthreads();
  }
}

// ---------------- legacy main kernel (no-workspace fallback) ----------------
__global__ __launch_bounds__(512, 2) void router_main_legacy(
    const float* __restrict__ feat, const float* __restrict__ W1,
    const float* __restrict__ b1, const float* __restrict__ W2,
    const float* __restrict__ b2, float* __restrict__ out,
    int* __restrict__ cnt, int* __restrict__ list, int cap)
{
  __shared__ __align__(16) unsigned char smem[49152];
  const int tid = threadIdx.x;
  const int w  = tid >> 6;
  const int l  = tid & 63;
  const int lr = l & 15;
  const int lg = l >> 4;
  const int wr = w >> 2;
  const int wc = w & 3;
  const int row0 = blockIdx.x * 128;

  floatx4 acc[4][4];
  const floatx4 z4 = {0.f, 0.f, 0.f, 0.f};
#pragma unroll
  for (int m = 0; m < 4; ++m)
#pragma unroll
    for (int n = 0; n < 4; ++n) acc[m][n] = z4;

  const int arow = tid >> 2;
  const int aq   = tid & 3;
  const int bcol = tid & 255;
  const int bh2  = tid >> 8;

  const float* aptr = feat + (size_t)(row0 + arow) * 1024 + aq * 8;
  const float* bptr = W1 + (size_t)(bh2 * 16) * 256 + bcol;

  const int L_AH = 0, L_AL = 8192, L_BH = 16384, L_BL = 32768;
  const int awo  = L_AH + arow * 64 + ((aq + (arow >> 1)) & 3) * 16;
  const int bg0  = bh2 * 2;
  const int bwo0 = L_BH + bcol * 64 + (((bg0    ) + (bcol >> 1)) & 3) * 16;
  const int bwo1 = L_BH + bcol * 64 + (((bg0 + 1) + (bcol >> 1)) & 3) * 16;

  float4 a0, a1;
  float pb[16];

  a0 = *(const float4*)(aptr);
  a1 = *(const float4*)(aptr + 4);
#pragma unroll
  for (int q = 0; q < 16; ++q) pb[q] = bptr[q * 256];

#pragma unroll 1
  for (int kt = 0; kt < 32; ++kt) {
    {
      float av[8] = {a0.x, a0.y, a0.z, a0.w, a1.x, a1.y, a1.z, a1.w};
      half8 hh, hl;
#pragma unroll
      for (int e = 0; e < 8; ++e) {
        float x = av[e] * 16.0f;
        _Float16 h = (_Float16)x;
        hh[e] = h;
        hl[e] = (_Float16)(x - (float)h);
      }
      *(half8*)(smem + awo)        = hh;
      *(half8*)(smem + awo + 8192) = hl;

      half8 c0h, c0l, c1h, c1l;
#pragma unroll
      for (int e = 0; e < 8; ++e) {
        float x = pb[e] * 64.0f;
        _Float16 h = (_Float16)x;
        c0h[e] = h; c0l[e] = (_Float16)(x - (float)h);
        float y = pb[e + 8] * 64.0f;
        _Float16 h2 = (_Float16)y;
        c1h[e] = h2; c1l[e] = (_Float16)(y - (float)h2);
      }
      *(half8*)(smem + bwo0)         = c0h;
      *(half8*)(smem + bwo0 + 16384) = c0l;
      *(half8*)(smem + bwo1)         = c1h;
      *(half8*)(smem + bwo1 + 16384) = c1l;
    }
    __syncthreads();
    if (kt + 1 < 32) {
      const float* ap = aptr + (kt + 1) * 32;
      a0 = *(const float4*)(ap);
      a1 = *(const float4*)(ap + 4);
      const float* bp = bptr + (size_t)(kt + 1) * 8192;
#pragma unroll
      for (int q = 0; q < 16; ++q) pb[q] = bp[q * 256];
    }
    {
      half8 bfh[4], bfl[4];
#pragma unroll
      for (int nf = 0; nf < 4; ++nf) {
        int c = wc * 64 + nf * 16 + lr;
        int off = c * 64 + ((lg + (c >> 1)) & 3) * 16;
        bfh[nf] = *(half8*)(smem + L_BH + off);
        bfl[nf] = *(half8*)(smem + L_BL + off);
      }
#pragma unroll
      for (int mf = 0; mf < 4; ++mf) {
        int r = wr * 64 + mf * 16 + lr;
        int off = r * 64 + ((lg + (r >> 1)) & 3) * 16;
        half8 ah  = *(half8*)(smem + L_AH + off);
        half8 al2 = *(half8*)(smem + L_AL + off);
#pragma unroll
        for (int nf = 0; nf < 4; ++nf) {
          acc[mf][nf] = __builtin_amdgcn_mfma_f32_16x16x32_f16(ah,  bfh[nf], acc[mf][nf], 0, 0, 0);
          acc[mf][nf] = __builtin_amdgcn_mfma_f32_16x16x32_f16(ah,  bfl[nf], acc[mf][nf], 0, 0, 0);
          acc[mf][nf] = __builtin_amdgcn_mfma_f32_16x16x32_f16(al2, bfh[nf], acc[mf][nf], 0, 0, 0);
        }
      }
    }
    __syncthreads();
  }

  half8 w2h[4], w2l[4];
#pragma unroll
  for (int ks = 0; ks < 4; ++ks)
#pragma unroll
    for (int jj = 0; jj < 8; ++jj) {
      int j = wr * 128 + ks * 32 + lg * 8 + jj;
      float v = W2[(size_t)j * 64 + wc * 16 + lr] * 64.0f;
      _Float16 h = (_Float16)v;
      w2h[ks][jj] = h;
      w2l[ks][jj] = (_Float16)(v - (float)h);
    }
  float b1v[4];
#pragma unroll
  for (int n = 0; n < 4; ++n) b1v[n] = b1[wc * 64 + n * 16 + lr];
  const int s_ep = tid & 15;
  const int r_ep = tid >> 4;
  float b2v[4];
#pragma unroll
  for (int n = 0; n < 4; ++n) b2v[n] = b2[s_ep + 16 * n];

  float* outU = out;
  float* outI = out + (size_t)NROWS * 64;
  float* outS = out + (size_t)NROWS * 64 + (size_t)NROWS * 3;

#pragma unroll
  for (int ch = 0; ch < 4; ++ch) {
    if (wr == (ch >> 1)) {
#pragma unroll
      for (int mm = 0; mm < 2; ++mm) {
        const int m = (ch & 1) * 2 + mm;
#pragma unroll
        for (int nf = 0; nf < 4; ++nf) {
#pragma unroll
          for (int q = 0; q < 4; ++q) {
            float z = acc[m][nf][q] * (1.0f / 1024.0f) + b1v[nf];
            float hs = gelu_exact(z) * 32.0f;
            _Float16 hi = (_Float16)hs;
            _Float16 lo = (_Float16)(hs - (float)hi);
            int rl = mm * 16 + lg * 4 + q;
            int cj = wc * 64 + nf * 16 + lr;
            int off = rl * 512 + (((cj >> 3) ^ (rl & 7)) * 16) + (cj & 7) * 2;
            *(_Float16*)(smem + H_H + off) = hi;
            *(_Float16*)(smem + H_L + off) = lo;
          }
        }
      }
    }
    __syncthreads();
    floatx4 acc2[2] = {z4, z4};
#pragma unroll
    for (int mf = 0; mf < 2; ++mf) {
      int rl = mf * 16 + lr;
#pragma unroll
      for (int ks = 0; ks < 4; ++ks) {
        int g = wr * 16 + ks * 4 + lg;
        int off = rl * 512 + ((g ^ (rl & 7)) * 16);
        half8 ha = *(half8*)(smem + H_H + off);
        half8 la = *(half8*)(smem + H_L + off);
        acc2[mf] = __builtin_amdgcn_mfma_f32_16x16x32_f16(ha, w2h[ks], acc2[mf], 0, 0, 0);
        acc2[mf] = __builtin_amdgcn_mfma_f32_16x16x32_f16(ha, w2l[ks], acc2[mf], 0, 0, 0);
        acc2[mf] = __builtin_amdgcn_mfma_f32_16x16x32_f16(la, w2h[ks], acc2[mf], 0, 0, 0);
      }
    }
    if (w >= 4) {
#pragma unroll
      for (int mf = 0; mf < 2; ++mf)
#pragma unroll
        for (int q = 0; q < 4; ++q) {
          int rp = mf * 16 + lg * 4 + q;
          int cp = wc * 16 + lr;
          *(float*)(smem + P_F + (rp * 64 + cp) * 4) = acc2[mf][q];
        }
    }
    __syncthreads();
    if (w < 4) {
#pragma unroll
      for (int mf = 0; mf < 2; ++mf)
#pragma unroll
        for (int q = 0; q < 4; ++q) {
          int rp = mf * 16 + lg * 4 + q;
          int cp = wc * 16 + lr;
          float* p = (float*)(smem + P_F + (rp * 64 + cp) * 4);
          *p = *p + acc2[mf][q];
        }
    }
    __syncthreads();
    {
      int rowg = row0 + ch * 32 + r_ep;
      float vals[4];
#pragma unroll
      for (int n = 0; n < 4; ++n)
        vals[n] = (*(float*)(smem + P_F + (r_ep * 64 + s_ep + 16 * n) * 4)) * (1.0f / 2048.0f) + b2v[n];

      float m1 = fmaxf(fmaxf(vals[0], vals[1]), fmaxf(vals[2], vals[3]));
#pragma unroll
      for (int d = 1; d < 16; d <<= 1) m1 = fmaxf(m1, __shfl_xor(m1, d));
      float e[4], ss = 0.f;
#pragma unroll
      for (int n = 0; n < 4; ++n) { e[n] = __expf(vals[n] - m1); ss += e[n]; }
#pragma unroll
      for (int d = 1; d < 16; d <<= 1) ss += __shfl_xor(ss, d);
      float inv = 1.0f / ss;
      float ps[4];
#pragma unroll
      for (int n = 0; n < 4; ++n) {
        ps[n] = e[n] * inv;
        outS[(size_t)rowg * 64 + s_ep + 16 * n] = ps[n];
      }
      float cur[4] = {vals[0], vals[1], vals[2], vals[3]};
      float tv[4]; int tc[4];
#pragma unroll
      for (int t = 0; t < 4; ++t) {
        float bv = -3.0e38f; int bc = 1 << 20;
#pragma unroll
        for (int n = 0; n < 4; ++n)
          if (cur[n] > bv) { bv = cur[n]; bc = s_ep + 16 * n; }
#pragma unroll
        for (int d = 1; d < 16; d <<= 1) {
          float ov = __shfl_xor(bv, d);
          int  oc = __shfl_xor(bc, d);
          if (ov > bv || (ov == bv && oc < bc)) { bv = ov; bc = oc; }
        }
        tv[t] = bv; tc[t] = bc;
#pragma unroll
        for (int n = 0; n < 4; ++n) if (s_ep + 16 * n == bc) cur[n] = -3.0e38f;
      }
      float l2[4];
#pragma unroll
      for (int n = 0; n < 4; ++n) {
        float p = fmaxf(ps[n], 1e-12f);
        float p2 = p * p;
        float p4 = p2 * p2;
        float lgv = logf(p4 + 1e-12f);
        int c = s_ep + 16 * n;
        bool top = (c == tc[0]) | (c == tc[1]) | (c == tc[2]);
        l2[n] = 10.0f * lgv + (top ? 0.0f : -46.051701859880914f);
      }
      float m2 = fmaxf(fmaxf(l2[0], l2[1]), fmaxf(l2[2], l2[3]));
#pragma unroll
      for (int d = 1; d < 16; d <<= 1) m2 = fmaxf(m2, __shfl_xor(m2, d));
      float e2[4], s2 = 0.f;
#pragma unroll
      for (int n = 0; n < 4; ++n) { e2[n] = __expf(l2[n] - m2); s2 += e2[n]; }
#pragma unroll
      for (int d = 1; d < 16; d <<= 1) s2 += __shfl_xor(s2, d);
      float inv2 = 1.0f / s2;
#pragma unroll
      for (int n = 0; n < 4; ++n) outU[(size_t)rowg * 64 + s_ep + 16 * n] = e2[n] * inv2;

      if (s_ep == 0) {
        outI[(size_t)rowg * 3 + 0] = (float)tc[0];
        outI[(size_t)rowg * 3 + 1] = (float)tc[1];
        outI[(size_t)rowg * 3 + 2] = (float)tc[2];
        float mg = fminf(tv[0] - tv[1], fminf(tv[1] - tv[2], tv[2] - tv[3]));
        if (mg < TAU && cap > 0) {
          int pos = atomicAdd(cnt, 1);
          if (pos < cap) list[pos] = rowg;
        }
      }
    }
    __syncthreads();
  }
}

// fp64 refinement of near-tie rows: recompute logits exactly, overwrite idx.
__global__ __launch_bounds__(256, 4) void router_refine(
    const float* __restrict__ feat, const float* __restrict__ W1,
    const float* __restrict__ b1, const float* __restrict__ W2,
    const float* __restrict__ b2, float* __restrict__ out,
    const int* __restrict__ cnt, const int* __restrict__ list, int cap)
{
  __shared__ float  fbuf[4][1024];
  __shared__ double hbuf[4][256];
  int n = *cnt; if (n > cap) n = cap;
  if (n <= 0) return;
  const int tid = threadIdx.x;
  const int wv = tid >> 6;
  const int l  = tid & 63;
  float* outI = out + (size_t)NROWS * 64;
#pragma unroll 1
  for (int base = blockIdx.x * 4; base < n; base += 4096) {
    int nrows = n - base; if (nrows > 4) nrows = 4;
    for (int rr = 0; rr < 4; ++rr) {
      if (rr < nrows) {
        int row = list[base + rr];
        for (int i = tid; i < 1024; i += 256) fbuf[rr][i] = feat[(size_t)row * 1024 + i];
      }
    }
    __syncthreads();
    if (wv < nrows) {
      double zq0 = 0, zq1 = 0, zq2 = 0, zq3 = 0;
#pragma unroll 4
      for (int i = 0; i < 1024; ++i) {
        double f = (double)fbuf[wv][i];
        const float* wrow = W1 + (size_t)i * 256 + l;
        zq0 += f * (double)wrow[0];
        zq1 += f * (double)wrow[64];
        zq2 += f * (double)wrow[128];
        zq3 += f * (double)wrow[192];
      }
      double zz[4] = {zq0 + (double)b1[l],       zq1 + (double)b1[l + 64],
                      zq2 + (double)b1[l + 128], zq3 + (double)b1[l + 192]};
#pragma unroll
      for (int q = 0; q < 4; ++q) {
        double z = zz[q];
        hbuf[wv][l + 64 * q] = 0.5 * z * (1.0 + erf(z * 0.70710678118654752440));
      }
    }
    __syncthreads();
    if (wv < nrows) {
      double lgt = (double)b2[l];
#pragma unroll 4
      for (int j = 0; j < 256; ++j) lgt += hbuf[wv][j] * (double)W2[(size_t)j * 64 + l];
      int chosen[3];
      double curv = lgt;
      for (int t = 0; t < 3; ++t) {
        double mv = curv; int mc = l;
        for (int d = 1; d < 64; d <<= 1) {
          double ov = __shfl_xor(mv, d);
          int   oc = __shfl_xor(mc, d);
          if (ov > mv || (ov == mv && oc < mc)) { mv = ov; mc = oc; }
        }
        chosen[t] = mc;
        if (l == mc) curv = -1.0e300;
      }
      if (l == 0) {
        int row = list[base + wv];
        outI[(size_t)row * 3 + 0] = (float)chosen[0];
        outI[(size_t)row * 3 + 1] = (float)chosen[1];
        outI[(size_t)row * 3 + 2] = (float)chosen[2];
      }
    }
    __syncthreads();
  }
}

extern "C" void kernel_launch(void* const* d_in, const int* in_sizes, int n_in,
                              void* d_out, int out_size, void* d_ws, size_t ws_size,
                              hipStream_t stream) {
  (void)in_sizes; (void)n_in; (void)out_size;
  const float* feat = (const float*)d_in[0];
  const float* W1   = (const float*)d_in[1];
  const float* b1   = (const float*)d_in[2];
  const float* W2   = (const float*)d_in[3];
  const float* b2   = (const float*)d_in[4];
  float* out = (float*)d_out;

  size_t need_fused = (size_t)W1S_BYTES + 4 + 16384;
  size_t need_split = (size_t)W1S_BYTES + H_BYTES + 4 + 16384;

  if (ws_size >= need_split) {
    unsigned char* w1s = (unsigned char*)d_ws;
    float* hbuf = (float*)(w1s + W1S_BYTES);
    int* cnt  = (int*)((unsigned char*)d_ws + W1S_BYTES + H_BYTES);
    int* list = cnt + 1;
    long capl = (long)((ws_size - W1S_BYTES - H_BYTES - 4) / 4);
    int cap = capl > 65536 ? 65536 : (int)capl;
    hipLaunchKernelGGL(router_prep, dim3(128), dim3(256), 0, stream, W1, w1s, cnt);
    hipLaunchKernelGGL(router_gemm1, dim3(NROWS / BM1), dim3(512), 0, stream,
                       feat, w1s, b1, hbuf);
    hipLaunchKernelGGL(router_gemm2, dim3(NROWS / 32), dim3(512), 0, stream,
                       hbuf, W2, b2, out, cnt, list, cap);
    hipLaunchKernelGGL(router_refine, dim3(1024), dim3(256), 0, stream,
                       feat, W1, b1, W2, b2, out, cnt, list, cap);
  } else if (ws_size >= need_fused) {
    unsigned char* w1s = (unsigned char*)d_ws;
    int* cnt  = (int*)(w1s + W1S_BYTES);
    int* list = cnt + 1;
    long capl = (long)((ws_size - W1S_BYTES - 4) / 4);
    int cap = capl > 65536 ? 65536 : (int)capl;
    hipLaunchKernelGGL(router_prep, dim3(128), dim3(256), 0, stream, W1, w1s, cnt);
    hipLaunchKernelGGL(router_fused, dim3(NROWS / 128), dim3(512), 0, stream,
                       feat, w1s, b1, W2, b2, out, cnt, list, cap);
    hipLaunchKernelGGL(router_refine, dim3(1024), dim3(256), 0, stream,
                       feat, W1, b1, W2, b2, out, cnt, list, cap);
  } else {
    int* cnt  = (int*)d_ws;
    int* list = cnt + 1;
    long capl = (ws_size >= 8) ? (long)(ws_size / 4) - 1 : 0;
    int cap = capl < 0 ? 0 : (capl > 65536 ? 65536 : (int)capl);
    if (cap > 0) hipMemsetAsync(cnt, 0, sizeof(int), stream);
    hipLaunchKernelGGL(router_main_legacy, dim3(NROWS / 128), dim3(512), 0, stream,
                       feat, W1, b1, W2, b2, out, cnt, list, cap);
    if (cap > 0)
      hipLaunchKernelGGL(router_refine, dim3(1024), dim3(256), 0, stream,
                         feat, W1, b1, W2, b2, out, cnt, list, cap);
  }
}

// Round 12
// 445.479 us; speedup vs baseline: 1.0900x; 1.0900x over previous
//
#include <hip/hip_runtime.h>
#include <math.h>

typedef _Float16 half8 __attribute__((ext_vector_type(8)));
typedef _Float16 half4 __attribute__((ext_vector_type(4)));
typedef float floatx4 __attribute__((ext_vector_type(4)));

#define NROWS 131072
#define BM1 128
#define W1S_BYTES (32 * 32768)
#define H_BYTES ((size_t)NROWS * 256 * 4)

// ---- gemm1 / fused LDS map (96 KiB): double-buffered A and B (r6 layout) ----
#define A0b 0
#define A1b 16384
#define B0b 32768
#define B1b 65536
// ---- phase-2 map: H: [32][512B] per plane (XOR-swizzled); P: [32][64] f32
#define H_H 0
#define H_L 16384
#define P_F 32768

#define TAU 1e-4f

__device__ __forceinline__ float gelu_exact(float z) {
  return 0.5f * z * (1.0f + erff(z * 0.70710678118654752f));
}

// Pre-split W1 (scale 64) into per-k-tile images laid out byte-identically to
// the LDS B-tile; also zeroes the tie-list counter.
__global__ __launch_bounds__(256) void router_prep(const float* __restrict__ W1,
                                                   unsigned char* __restrict__ w1s,
                                                   int* __restrict__ cnt) {
  if (blockIdx.x == 0 && threadIdx.x == 0) *cnt = 0;
  int p = blockIdx.x * 256 + threadIdx.x;
  int col = p & 255;
  int g   = (p >> 8) & 3;
  int kt  = p >> 10;
  half8 hh, hl;
#pragma unroll
  for (int e = 0; e < 8; ++e) {
    float v = W1[(size_t)(kt * 32 + g * 8 + e) * 256 + col] * 64.0f;
    _Float16 h = (_Float16)v;
    hh[e] = h;
    hl[e] = (_Float16)(v - (float)h);
  }
  int off = col * 64 + ((g + (col >> 1)) & 3) * 16;
  unsigned char* base = w1s + (size_t)kt * 32768;
  *(half8*)(base + off) = hh;
  *(half8*)(base + 16384 + off) = hl;
}

// ---------------- 512-thread macros (fused fallback; r9-proven) ------------
#define GLDS_B(KT, BB) do {                                                  \
    const unsigned char* gp_ = w1s + (size_t)(KT) * 32768 + tid * 16;        \
    _Pragma("unroll") for (int j_ = 0; j_ < 4; ++j_) {                       \
      __builtin_amdgcn_global_load_lds(                                      \
        (const __attribute__((address_space(1))) void*)(gp_ + j_ * 8192),    \
        (__attribute__((address_space(3))) void*)(smem + (BB) + (w << 10) + j_ * 8192), \
        16, 0, 0);                                                           \
    }                                                                        \
  } while (0)

#define LOAD_A(KT, A0, A1) do {                                              \
    const float* ap_ = aptr + (KT) * 32;                                     \
    A0 = *(const float4*)(ap_);                                              \
    A1 = *(const float4*)(ap_ + 4);                                          \
  } while (0)

#define STAGE_A(A0, A1, AB) do {                                             \
    float av_[8] = {A0.x, A0.y, A0.z, A0.w, A1.x, A1.y, A1.z, A1.w};         \
    half8 hh_, hl_;                                                          \
    _Pragma("unroll") for (int e_ = 0; e_ < 8; ++e_) {                       \
      float x_ = av_[e_] * 16.0f;                                            \
      _Float16 h_ = (_Float16)x_;                                            \
      hh_[e_] = h_;                                                          \
      hl_[e_] = (_Float16)(x_ - (float)h_);                                  \
    }                                                                        \
    *(half8*)(smem + (AB) + awo)        = hh_;                               \
    *(half8*)(smem + (AB) + awo + 8192) = hl_;                               \
  } while (0)

#define MFMA_STEP(AB, BB) do {                                               \
    half8 bfh_[4], bfl_[4];                                                  \
    _Pragma("unroll") for (int nf_ = 0; nf_ < 4; ++nf_) {                    \
      int c_ = wc * 64 + nf_ * 16 + lr;                                      \
      int off_ = c_ * 64 + ((lg + (c_ >> 1)) & 3) * 16;                      \
      bfh_[nf_] = *(half8*)(smem + (BB) + off_);                             \
      bfl_[nf_] = *(half8*)(smem + (BB) + 16384 + off_);                     \
    }                                                                        \
    _Pragma("unroll") for (int mf_ = 0; mf_ < 4; ++mf_) {                    \
      int r_ = wr * 64 + mf_ * 16 + lr;                                      \
      int off_ = r_ * 64 + ((lg + (r_ >> 1)) & 3) * 16;                      \
      half8 ah_  = *(half8*)(smem + (AB) + off_);                            \
      half8 al_  = *(half8*)(smem + (AB) + 8192 + off_);                     \
      _Pragma("unroll") for (int nf_ = 0; nf_ < 4; ++nf_) {                  \
        acc[mf_][nf_] = __builtin_amdgcn_mfma_f32_16x16x32_f16(ah_, bfh_[nf_], acc[mf_][nf_], 0, 0, 0); \
        acc[mf_][nf_] = __builtin_amdgcn_mfma_f32_16x16x32_f16(ah_, bfl_[nf_], acc[mf_][nf_], 0, 0, 0); \
        acc[mf_][nf_] = __builtin_amdgcn_mfma_f32_16x16x32_f16(al_, bfh_[nf_], acc[mf_][nf_], 0, 0, 0); \
      }                                                                      \
    }                                                                        \
  } while (0)

// ---------------- 1024-thread macros (gemm1; 16 waves, acc[4][2]) ----------
#define GLDS_B16(KT, BB) do {                                                \
    const unsigned char* gp_ = w1s + (size_t)(KT) * 32768 + tid * 16;        \
    _Pragma("unroll") for (int j_ = 0; j_ < 2; ++j_) {                       \
      __builtin_amdgcn_global_load_lds(                                      \
        (const __attribute__((address_space(1))) void*)(gp_ + j_ * 16384),   \
        (__attribute__((address_space(3))) void*)(smem + (BB) + (w << 10) + j_ * 16384), \
        16, 0, 0);                                                           \
    }                                                                        \
  } while (0)

#define LOAD_A16(KT, A0) do {                                                \
    A0 = *(const float4*)(aptr + (KT) * 32);                                 \
  } while (0)

#define STAGE_A16(A0, AB) do {                                               \
    float av_[4] = {A0.x, A0.y, A0.z, A0.w};                                 \
    half4 hh_, hl_;                                                          \
    _Pragma("unroll") for (int e_ = 0; e_ < 4; ++e_) {                       \
      float x_ = av_[e_] * 16.0f;                                            \
      _Float16 h_ = (_Float16)x_;                                            \
      hh_[e_] = h_;                                                          \
      hl_[e_] = (_Float16)(x_ - (float)h_);                                  \
    }                                                                        \
    *(half4*)(smem + (AB) + awo)        = hh_;                               \
    *(half4*)(smem + (AB) + awo + 8192) = hl_;                               \
  } while (0)

#define MFMA_STEP16(AB, BB) do {                                             \
    half8 bfh_[2], bfl_[2];                                                  \
    _Pragma("unroll") for (int nf_ = 0; nf_ < 2; ++nf_) {                    \
      int c_ = wc8 * 32 + nf_ * 16 + lr;                                     \
      int off_ = c_ * 64 + ((lg + (c_ >> 1)) & 3) * 16;                      \
      bfh_[nf_] = *(half8*)(smem + (BB) + off_);                             \
      bfl_[nf_] = *(half8*)(smem + (BB) + 16384 + off_);                     \
    }                                                                        \
    _Pragma("unroll") for (int mf_ = 0; mf_ < 4; ++mf_) {                    \
      int r_ = wr * 64 + mf_ * 16 + lr;                                      \
      int off_ = r_ * 64 + ((lg + (r_ >> 1)) & 3) * 16;                      \
      half8 ah_  = *(half8*)(smem + (AB) + off_);                            \
      half8 al_  = *(half8*)(smem + (AB) + 8192 + off_);                     \
      _Pragma("unroll") for (int nf_ = 0; nf_ < 2; ++nf_) {                  \
        acc[mf_][nf_] = __builtin_amdgcn_mfma_f32_16x16x32_f16(ah_, bfh_[nf_], acc[mf_][nf_], 0, 0, 0); \
        acc[mf_][nf_] = __builtin_amdgcn_mfma_f32_16x16x32_f16(ah_, bfl_[nf_], acc[mf_][nf_], 0, 0, 0); \
        acc[mf_][nf_] = __builtin_amdgcn_mfma_f32_16x16x32_f16(al_, bfh_[nf_], acc[mf_][nf_], 0, 0, 0); \
      }                                                                      \
    }                                                                        \
  } while (0)

// ================= GEMM1: h = gelu(feat @ W1 + b1) -> ws (f32) =============
// 1024 threads (16 waves = 4 waves/SIMD): same traffic/LDS/barriers as r9,
// only intra-block wave parallelism doubled. acc[4][2] per wave.
__global__ __launch_bounds__(1024, 4) void router_gemm1(
    const float* __restrict__ feat, const unsigned char* __restrict__ w1s,
    const float* __restrict__ b1, float* __restrict__ hbuf)
{
  __shared__ __align__(16) unsigned char smem[98304];
  const int tid = threadIdx.x;
  const int w  = tid >> 6;     // wave 0..15
  const int l  = tid & 63;
  const int lr = l & 15;
  const int lg = l >> 4;
  const int wr  = w >> 3;      // 0..1 : row half
  const int wc8 = w & 7;       // 0..7 : col eighth (32 cols)
  const int row0 = blockIdx.x * BM1;

  floatx4 acc[4][2];           // 32 AGPRs; compile-time indexed only
  const floatx4 z4 = {0.f, 0.f, 0.f, 0.f};
#pragma unroll
  for (int m = 0; m < 4; ++m)
#pragma unroll
    for (int n = 0; n < 2; ++n) acc[m][n] = z4;

  // A staging: 128 rows x 32 k floats = 4096 = 1024 threads x 1 float4
  const int arow = tid >> 3;          // 0..127
  const int ag   = (tid >> 1) & 3;    // granule 0..3
  const int ahf  = tid & 1;           // 16B half of the 32B granule slot
  const float* aptr = feat + (size_t)(row0 + arow) * 1024 + ag * 8 + ahf * 4;
  const int awo = arow * 64 + ((ag + (arow >> 1)) & 3) * 16 + ahf * 8;

  float4 aE0, aO0;

  GLDS_B16(0, B0b);
  LOAD_A16(0, aE0);
  LOAD_A16(1, aO0);
  STAGE_A16(aE0, A0b);
  __syncthreads();

#pragma unroll 1
  for (int kt = 0; kt < 32; kt += 2) {
    GLDS_B16(kt + 1, B1b);
    if (kt + 2 < 32) LOAD_A16(kt + 2, aE0);
    STAGE_A16(aO0, A1b);
    MFMA_STEP16(A0b, B0b);
    __syncthreads();
    if (kt + 2 < 32) {
      GLDS_B16(kt + 2, B0b);
      STAGE_A16(aE0, A0b);
    }
    if (kt + 3 < 32) LOAD_A16(kt + 3, aO0);
    MFMA_STEP16(A1b, B1b);
    __syncthreads();
  }

  // epilogue: h = gelu(z) -> global f32 (exact; same values as fused path)
  float b1v[2];
#pragma unroll
  for (int n = 0; n < 2; ++n) b1v[n] = b1[wc8 * 32 + n * 16 + lr];
#pragma unroll
  for (int m = 0; m < 4; ++m)
#pragma unroll
    for (int nf = 0; nf < 2; ++nf)
#pragma unroll
      for (int q = 0; q < 4; ++q) {
        float z = acc[m][nf][q] * (1.0f / 1024.0f) + b1v[nf];
        float hv = gelu_exact(z);
        int r = wr * 64 + m * 16 + lg * 4 + q;
        int c = wc8 * 32 + nf * 16 + lr;
        hbuf[(size_t)(row0 + r) * 256 + c] = hv;
      }
}

// ================= GEMM2: logits/softmax/topk from h (unchanged from r9) ===
__global__ __launch_bounds__(512, 4) void router_gemm2(
    const float* __restrict__ hbuf, const float* __restrict__ W2,
    const float* __restrict__ b2, float* __restrict__ out,
    int* __restrict__ cnt, int* __restrict__ list, int cap)
{
  __shared__ __align__(16) unsigned char smem[40960];
  const int tid = threadIdx.x;
  const int w  = tid >> 6;
  const int l  = tid & 63;
  const int lr = l & 15;
  const int lg = l >> 4;
  const int wr = w >> 2;     // k half
  const int wc = w & 3;      // col frag
  const int row0 = blockIdx.x * 32;
  const floatx4 z4 = {0.f, 0.f, 0.f, 0.f};

  half8 w2h[4], w2l[4];
#pragma unroll
  for (int ks = 0; ks < 4; ++ks)
#pragma unroll
    for (int jj = 0; jj < 8; ++jj) {
      int j = wr * 128 + ks * 32 + lg * 8 + jj;
      float v = W2[(size_t)j * 64 + wc * 16 + lr] * 64.0f;
      _Float16 h = (_Float16)v;
      w2h[ks][jj] = h;
      w2l[ks][jj] = (_Float16)(v - (float)h);
    }
  const int s_ep = tid & 15;
  const int r_ep = tid >> 4;   // 0..31
  float b2v[4];
#pragma unroll
  for (int n = 0; n < 4; ++n) b2v[n] = b2[s_ep + 16 * n];

  // stage h rows (scale 32, split f16) into XOR-swizzled LDS
  {
    const int hr  = tid >> 4;         // 0..31
    const int hc0 = (tid & 15) * 16;  // 16 cols per thread
    const float* hp = hbuf + (size_t)(row0 + hr) * 256 + hc0;
    float4 hv0 = *(const float4*)(hp);
    float4 hv1 = *(const float4*)(hp + 4);
    float4 hv2 = *(const float4*)(hp + 8);
    float4 hv3 = *(const float4*)(hp + 12);
    float hvs[16] = {hv0.x, hv0.y, hv0.z, hv0.w, hv1.x, hv1.y, hv1.z, hv1.w,
                     hv2.x, hv2.y, hv2.z, hv2.w, hv3.x, hv3.y, hv3.z, hv3.w};
#pragma unroll
    for (int j = 0; j < 16; ++j) {
      float hs = hvs[j] * 32.0f;
      _Float16 hi = (_Float16)hs;
      _Float16 lo = (_Float16)(hs - (float)hi);
      int cj = hc0 + j;
      int off = hr * 512 + (((cj >> 3) ^ (hr & 7)) * 16) + (cj & 7) * 2;
      *(_Float16*)(smem + H_H + off) = hi;
      *(_Float16*)(smem + H_L + off) = lo;
    }
  }
  __syncthreads();

  floatx4 acc2[2] = {z4, z4};
#pragma unroll
  for (int mf = 0; mf < 2; ++mf) {
    int rl = mf * 16 + lr;
#pragma unroll
    for (int ks = 0; ks < 4; ++ks) {
      int g = wr * 16 + ks * 4 + lg;
      int off = rl * 512 + ((g ^ (rl & 7)) * 16);
      half8 ha = *(half8*)(smem + H_H + off);
      half8 la = *(half8*)(smem + H_L + off);
      acc2[mf] = __builtin_amdgcn_mfma_f32_16x16x32_f16(ha, w2h[ks], acc2[mf], 0, 0, 0);
      acc2[mf] = __builtin_amdgcn_mfma_f32_16x16x32_f16(ha, w2l[ks], acc2[mf], 0, 0, 0);
      acc2[mf] = __builtin_amdgcn_mfma_f32_16x16x32_f16(la, w2h[ks], acc2[mf], 0, 0, 0);
    }
  }
  if (w >= 4) {
#pragma unroll
    for (int mf = 0; mf < 2; ++mf)
#pragma unroll
      for (int q = 0; q < 4; ++q) {
        int rp = mf * 16 + lg * 4 + q;
        int cp = wc * 16 + lr;
        *(float*)(smem + P_F + (rp * 64 + cp) * 4) = acc2[mf][q];
      }
  }
  __syncthreads();
  if (w < 4) {
#pragma unroll
    for (int mf = 0; mf < 2; ++mf)
#pragma unroll
      for (int q = 0; q < 4; ++q) {
        int rp = mf * 16 + lg * 4 + q;
        int cp = wc * 16 + lr;
        float* p = (float*)(smem + P_F + (rp * 64 + cp) * 4);
        *p = *p + acc2[mf][q];
      }
  }
  __syncthreads();

  float* outU = out;
  float* outI = out + (size_t)NROWS * 64;
  float* outS = out + (size_t)NROWS * 64 + (size_t)NROWS * 3;

  {
    int rowg = row0 + r_ep;
    float vals[4];
#pragma unroll
    for (int n = 0; n < 4; ++n)
      vals[n] = (*(float*)(smem + P_F + (r_ep * 64 + s_ep + 16 * n) * 4)) * (1.0f / 2048.0f) + b2v[n];

    float m1 = fmaxf(fmaxf(vals[0], vals[1]), fmaxf(vals[2], vals[3]));
#pragma unroll
    for (int d = 1; d < 16; d <<= 1) m1 = fmaxf(m1, __shfl_xor(m1, d));
    float e[4], ss = 0.f;
#pragma unroll
    for (int n = 0; n < 4; ++n) { e[n] = __expf(vals[n] - m1); ss += e[n]; }
#pragma unroll
    for (int d = 1; d < 16; d <<= 1) ss += __shfl_xor(ss, d);
    float inv = 1.0f / ss;
    float ps[4];
#pragma unroll
    for (int n = 0; n < 4; ++n) {
      ps[n] = e[n] * inv;
      outS[(size_t)rowg * 64 + s_ep + 16 * n] = ps[n];
    }
    float cur[4] = {vals[0], vals[1], vals[2], vals[3]};
    float tv[4]; int tc[4];
#pragma unroll
    for (int t = 0; t < 4; ++t) {
      float bv = -3.0e38f; int bc = 1 << 20;
#pragma unroll
      for (int n = 0; n < 4; ++n)
        if (cur[n] > bv) { bv = cur[n]; bc = s_ep + 16 * n; }
#pragma unroll
      for (int d = 1; d < 16; d <<= 1) {
        float ov = __shfl_xor(bv, d);
        int  oc = __shfl_xor(bc, d);
        if (ov > bv || (ov == bv && oc < bc)) { bv = ov; bc = oc; }
      }
      tv[t] = bv; tc[t] = bc;
#pragma unroll
      for (int n = 0; n < 4; ++n) if (s_ep + 16 * n == bc) cur[n] = -3.0e38f;
    }
    float l2[4];
#pragma unroll
    for (int n = 0; n < 4; ++n) {
      float p = fmaxf(ps[n], 1e-12f);
      float p2 = p * p;
      float p4 = p2 * p2;
      float lgv = logf(p4 + 1e-12f);
      int c = s_ep + 16 * n;
      bool top = (c == tc[0]) | (c == tc[1]) | (c == tc[2]);
      l2[n] = 10.0f * lgv + (top ? 0.0f : -46.051701859880914f);
    }
    float m2 = fmaxf(fmaxf(l2[0], l2[1]), fmaxf(l2[2], l2[3]));
#pragma unroll
    for (int d = 1; d < 16; d <<= 1) m2 = fmaxf(m2, __shfl_xor(m2, d));
    float e2[4], s2 = 0.f;
#pragma unroll
    for (int n = 0; n < 4; ++n) { e2[n] = __expf(l2[n] - m2); s2 += e2[n]; }
#pragma unroll
    for (int d = 1; d < 16; d <<= 1) s2 += __shfl_xor(s2, d);
    float inv2 = 1.0f / s2;
#pragma unroll
    for (int n = 0; n < 4; ++n) outU[(size_t)rowg * 64 + s_ep + 16 * n] = e2[n] * inv2;

    if (s_ep == 0) {
      outI[(size_t)rowg * 3 + 0] = (float)tc[0];
      outI[(size_t)rowg * 3 + 1] = (float)tc[1];
      outI[(size_t)rowg * 3 + 2] = (float)tc[2];
      float mg = fminf(tv[0] - tv[1], fminf(tv[1] - tv[2], tv[2] - tv[3]));
      if (mg < TAU && cap > 0) {
        int pos = atomicAdd(cnt, 1);
        if (pos < cap) list[pos] = rowg;
      }
    }
  }
}

// ================= fused fallback (r6 winner, BM=128, __syncthreads) =======
__global__ __launch_bounds__(512, 2) void router_fused(
    const float* __restrict__ feat, const unsigned char* __restrict__ w1s,
    const float* __restrict__ b1, const float* __restrict__ W2,
    const float* __restrict__ b2, float* __restrict__ out,
    int* __restrict__ cnt, int* __restrict__ list, int cap)
{
  __shared__ __align__(16) unsigned char smem[98304];
  const int tid = threadIdx.x;
  const int w  = tid >> 6;
  const int l  = tid & 63;
  const int lr = l & 15;
  const int lg = l >> 4;
  const int wr = w >> 2;
  const int wc = w & 3;
  const int row0 = blockIdx.x * 128;

  floatx4 acc[4][4];
  const floatx4 z4 = {0.f, 0.f, 0.f, 0.f};
#pragma unroll
  for (int m = 0; m < 4; ++m)
#pragma unroll
    for (int n = 0; n < 4; ++n) acc[m][n] = z4;

  const int arow = tid >> 2;
  const int aq   = tid & 3;
  const float* aptr = feat + (size_t)(row0 + arow) * 1024 + aq * 8;
  const int awo = arow * 64 + ((aq + (arow >> 1)) & 3) * 16;

  float4 aE0, aE1, aO0, aO1;

  GLDS_B(0, B0b);
  LOAD_A(0, aE0, aE1);
  LOAD_A(1, aO0, aO1);
  STAGE_A(aE0, aE1, A0b);
  __syncthreads();

#pragma unroll 1
  for (int kt = 0; kt < 32; kt += 2) {
    GLDS_B(kt + 1, B1b);
    if (kt + 2 < 32) LOAD_A(kt + 2, aE0, aE1);
    STAGE_A(aO0, aO1, A1b);
    MFMA_STEP(A0b, B0b);
    __syncthreads();
    if (kt + 2 < 32) {
      GLDS_B(kt + 2, B0b);
      STAGE_A(aE0, aE1, A0b);
    }
    if (kt + 3 < 32) LOAD_A(kt + 3, aO0, aO1);
    MFMA_STEP(A1b, B1b);
    __syncthreads();
  }

  half8 w2h[4], w2l[4];
#pragma unroll
  for (int ks = 0; ks < 4; ++ks)
#pragma unroll
    for (int jj = 0; jj < 8; ++jj) {
      int j = wr * 128 + ks * 32 + lg * 8 + jj;
      float v = W2[(size_t)j * 64 + wc * 16 + lr] * 64.0f;
      _Float16 h = (_Float16)v;
      w2h[ks][jj] = h;
      w2l[ks][jj] = (_Float16)(v - (float)h);
    }
  float b1v[4];
#pragma unroll
  for (int n = 0; n < 4; ++n) b1v[n] = b1[wc * 64 + n * 16 + lr];
  const int s_ep = tid & 15;
  const int r_ep = tid >> 4;
  float b2v[4];
#pragma unroll
  for (int n = 0; n < 4; ++n) b2v[n] = b2[s_ep + 16 * n];

  float* outU = out;
  float* outI = out + (size_t)NROWS * 64;
  float* outS = out + (size_t)NROWS * 64 + (size_t)NROWS * 3;

#pragma unroll
  for (int ch = 0; ch < 4; ++ch) {
    if (wr == (ch >> 1)) {
#pragma unroll
      for (int mm = 0; mm < 2; ++mm) {
        const int m = (ch & 1) * 2 + mm;
#pragma unroll
        for (int nf = 0; nf < 4; ++nf) {
#pragma unroll
          for (int q = 0; q < 4; ++q) {
            float z = acc[m][nf][q] * (1.0f / 1024.0f) + b1v[nf];
            float hs = gelu_exact(z) * 32.0f;
            _Float16 hi = (_Float16)hs;
            _Float16 lo = (_Float16)(hs - (float)hi);
            int rl = mm * 16 + lg * 4 + q;
            int cj = wc * 64 + nf * 16 + lr;
            int off = rl * 512 + (((cj >> 3) ^ (rl & 7)) * 16) + (cj & 7) * 2;
            *(_Float16*)(smem + H_H + off) = hi;
            *(_Float16*)(smem + H_L + off) = lo;
          }
        }
      }
    }
    __syncthreads();
    floatx4 acc2[2] = {z4, z4};
#pragma unroll
    for (int mf = 0; mf < 2; ++mf) {
      int rl = mf * 16 + lr;
#pragma unroll
      for (int ks = 0; ks < 4; ++ks) {
        int g = wr * 16 + ks * 4 + lg;
        int off = rl * 512 + ((g ^ (rl & 7)) * 16);
        half8 ha = *(half8*)(smem + H_H + off);
        half8 la = *(half8*)(smem + H_L + off);
        acc2[mf] = __builtin_amdgcn_mfma_f32_16x16x32_f16(ha, w2h[ks], acc2[mf], 0, 0, 0);
        acc2[mf] = __builtin_amdgcn_mfma_f32_16x16x32_f16(ha, w2l[ks], acc2[mf], 0, 0, 0);
        acc2[mf] = __builtin_amdgcn_mfma_f32_16x16x32_f16(la, w2h[ks], acc2[mf], 0, 0, 0);
      }
    }
    if (w >= 4) {
#pragma unroll
      for (int mf = 0; mf < 2; ++mf)
#pragma unroll
        for (int q = 0; q < 4; ++q) {
          int rp = mf * 16 + lg * 4 + q;
          int cp = wc * 16 + lr;
          *(float*)(smem + P_F + (rp * 64 + cp) * 4) = acc2[mf][q];
        }
    }
    __syncthreads();
    if (w < 4) {
#pragma unroll
      for (int mf = 0; mf < 2; ++mf)
#pragma unroll
        for (int q = 0; q < 4; ++q) {
          int rp = mf * 16 + lg * 4 + q;
          int cp = wc * 16 + lr;
          float* p = (float*)(smem + P_F + (rp * 64 + cp) * 4);
          *p = *p + acc2[mf][q];
        }
    }
    __syncthreads();
    {
      int rowg = row0 + ch * 32 + r_ep;
      float vals[4];
#pragma unroll
      for (int n = 0; n < 4; ++n)
        vals[n] = (*(float*)(smem + P_F + (r_ep * 64 + s_ep + 16 * n) * 4)) * (1.0f / 2048.0f) + b2v[n];

      float m1 = fmaxf(fmaxf(vals[0], vals[1]), fmaxf(vals[2], vals[3]));
#pragma unroll
      for (int d = 1; d < 16; d <<= 1) m1 = fmaxf(m1, __shfl_xor(m1, d));
      float e[4], ss = 0.f;
#pragma unroll
      for (int n = 0; n < 4; ++n) { e[n] = __expf(vals[n] - m1); ss += e[n]; }
#pragma unroll
      for (int d = 1; d < 16; d <<= 1) ss += __shfl_xor(ss, d);
      float inv = 1.0f / ss;
      float ps[4];
#pragma unroll
      for (int n = 0; n < 4; ++n) {
        ps[n] = e[n] * inv;
        outS[(size_t)rowg * 64 + s_ep + 16 * n] = ps[n];
      }
      float cur[4] = {vals[0], vals[1], vals[2], vals[3]};
      float tv[4]; int tc[4];
#pragma unroll
      for (int t = 0; t < 4; ++t) {
        float bv = -3.0e38f; int bc = 1 << 20;
#pragma unroll
        for (int n = 0; n < 4; ++n)
          if (cur[n] > bv) { bv = cur[n]; bc = s_ep + 16 * n; }
#pragma unroll
        for (int d = 1; d < 16; d <<= 1) {
          float ov = __shfl_xor(bv, d);
          int  oc = __shfl_xor(bc, d);
          if (ov > bv || (ov == bv && oc < bc)) { bv = ov; bc = oc; }
        }
        tv[t] = bv; tc[t] = bc;
#pragma unroll
        for (int n = 0; n < 4; ++n) if (s_ep + 16 * n == bc) cur[n] = -3.0e38f;
      }
      float l2[4];
#pragma unroll
      for (int n = 0; n < 4; ++n) {
        float p = fmaxf(ps[n], 1e-12f);
        float p2 = p * p;
        float p4 = p2 * p2;
        float lgv = logf(p4 + 1e-12f);
        int c = s_ep + 16 * n;
        bool top = (c == tc[0]) | (c == tc[1]) | (c == tc[2]);
        l2[n] = 10.0f * lgv + (top ? 0.0f : -46.051701859880914f);
      }
      float m2 = fmaxf(fmaxf(l2[0], l2[1]), fmaxf(l2[2], l2[3]));
#pragma unroll
      for (int d = 1; d < 16; d <<= 1) m2 = fmaxf(m2, __shfl_xor(m2, d));
      float e2[4], s2 = 0.f;
#pragma unroll
      for (int n = 0; n < 4; ++n) { e2[n] = __expf(l2[n] - m2); s2 += e2[n]; }
#pragma unroll
      for (int d = 1; d < 16; d <<= 1) s2 += __shfl_xor(s2, d);
      float inv2 = 1.0f / s2;
#pragma unroll
      for (int n = 0; n < 4; ++n) outU[(size_t)rowg * 64 + s_ep + 16 * n] = e2[n] * inv2;

      if (s_ep == 0) {
        outI[(size_t)rowg * 3 + 0] = (float)tc[0];
        outI[(size_t)rowg * 3 + 1] = (float)tc[1];
        outI[(size_t)rowg * 3 + 2] = (float)tc[2];
        float mg = fminf(tv[0] - tv[1], fminf(tv[1] - tv[2], tv[2] - tv[3]));
        if (mg < TAU && cap > 0) {
          int pos = atomicAdd(cnt, 1);
          if (pos < cap) list[pos] = rowg;
        }
      }
    }
    __syncthreads();
  }
}

// ---------------- legacy main kernel (no-workspace fallback) ----------------
__global__ __launch_bounds__(512, 2) void router_main_legacy(
    const float* __restrict__ feat, const float* __restrict__ W1,
    const float* __restrict__ b1, const float* __restrict__ W2,
    const float* __restrict__ b2, float* __restrict__ out,
    int* __restrict__ cnt, int* __restrict__ list, int cap)
{
  __shared__ __align__(16) unsigned char smem[49152];
  const int tid = threadIdx.x;
  const int w  = tid >> 6;
  const int l  = tid & 63;
  const int lr = l & 15;
  const int lg = l >> 4;
  const int wr = w >> 2;
  const int wc = w & 3;
  const int row0 = blockIdx.x * 128;

  floatx4 acc[4][4];
  const floatx4 z4 = {0.f, 0.f, 0.f, 0.f};
#pragma unroll
  for (int m = 0; m < 4; ++m)
#pragma unroll
    for (int n = 0; n < 4; ++n) acc[m][n] = z4;

  const int arow = tid >> 2;
  const int aq   = tid & 3;
  const int bcol = tid & 255;
  const int bh2  = tid >> 8;

  const float* aptr = feat + (size_t)(row0 + arow) * 1024 + aq * 8;
  const float* bptr = W1 + (size_t)(bh2 * 16) * 256 + bcol;

  const int L_AH = 0, L_AL = 8192, L_BH = 16384, L_BL = 32768;
  const int awo  = L_AH + arow * 64 + ((aq + (arow >> 1)) & 3) * 16;
  const int bg0  = bh2 * 2;
  const int bwo0 = L_BH + bcol * 64 + (((bg0    ) + (bcol >> 1)) & 3) * 16;
  const int bwo1 = L_BH + bcol * 64 + (((bg0 + 1) + (bcol >> 1)) & 3) * 16;

  float4 a0, a1;
  float pb[16];

  a0 = *(const float4*)(aptr);
  a1 = *(const float4*)(aptr + 4);
#pragma unroll
  for (int q = 0; q < 16; ++q) pb[q] = bptr[q * 256];

#pragma unroll 1
  for (int kt = 0; kt < 32; ++kt) {
    {
      float av[8] = {a0.x, a0.y, a0.z, a0.w, a1.x, a1.y, a1.z, a1.w};
      half8 hh, hl;
#pragma unroll
      for (int e = 0; e < 8; ++e) {
        float x = av[e] * 16.0f;
        _Float16 h = (_Float16)x;
        hh[e] = h;
        hl[e] = (_Float16)(x - (float)h);
      }
      *(half8*)(smem + awo)        = hh;
      *(half8*)(smem + awo + 8192) = hl;

      half8 c0h, c0l, c1h, c1l;
#pragma unroll
      for (int e = 0; e < 8; ++e) {
        float x = pb[e] * 64.0f;
        _Float16 h = (_Float16)x;
        c0h[e] = h; c0l[e] = (_Float16)(x - (float)h);
        float y = pb[e + 8] * 64.0f;
        _Float16 h2 = (_Float16)y;
        c1h[e] = h2; c1l[e] = (_Float16)(y - (float)h2);
      }
      *(half8*)(smem + bwo0)         = c0h;
      *(half8*)(smem + bwo0 + 16384) = c0l;
      *(half8*)(smem + bwo1)         = c1h;
      *(half8*)(smem + bwo1 + 16384) = c1l;
    }
    __syncthreads();
    if (kt + 1 < 32) {
      const float* ap = aptr + (kt + 1) * 32;
      a0 = *(const float4*)(ap);
      a1 = *(const float4*)(ap + 4);
      const float* bp = bptr + (size_t)(kt + 1) * 8192;
#pragma unroll
      for (int q = 0; q < 16; ++q) pb[q] = bp[q * 256];
    }
    {
      half8 bfh[4], bfl[4];
#pragma unroll
      for (int nf = 0; nf < 4; ++nf) {
        int c = wc * 64 + nf * 16 + lr;
        int off = c * 64 + ((lg + (c >> 1)) & 3) * 16;
        bfh[nf] = *(half8*)(smem + L_BH + off);
        bfl[nf] = *(half8*)(smem + L_BL + off);
      }
#pragma unroll
      for (int mf = 0; mf < 4; ++mf) {
        int r = wr * 64 + mf * 16 + lr;
        int off = r * 64 + ((lg + (r >> 1)) & 3) * 16;
        half8 ah  = *(half8*)(smem + L_AH + off);
        half8 al2 = *(half8*)(smem + L_AL + off);
#pragma unroll
        for (int nf = 0; nf < 4; ++nf) {
          acc[mf][nf] = __builtin_amdgcn_mfma_f32_16x16x32_f16(ah,  bfh[nf], acc[mf][nf], 0, 0, 0);
          acc[mf][nf] = __builtin_amdgcn_mfma_f32_16x16x32_f16(ah,  bfl[nf], acc[mf][nf], 0, 0, 0);
          acc[mf][nf] = __builtin_amdgcn_mfma_f32_16x16x32_f16(al2, bfh[nf], acc[mf][nf], 0, 0, 0);
        }
      }
    }
    __syncthreads();
  }

  half8 w2h[4], w2l[4];
#pragma unroll
  for (int ks = 0; ks < 4; ++ks)
#pragma unroll
    for (int jj = 0; jj < 8; ++jj) {
      int j = wr * 128 + ks * 32 + lg * 8 + jj;
      float v = W2[(size_t)j * 64 + wc * 16 + lr] * 64.0f;
      _Float16 h = (_Float16)v;
      w2h[ks][jj] = h;
      w2l[ks][jj] = (_Float16)(v - (float)h);
    }
  float b1v[4];
#pragma unroll
  for (int n = 0; n < 4; ++n) b1v[n] = b1[wc * 64 + n * 16 + lr];
  const int s_ep = tid & 15;
  const int r_ep = tid >> 4;
  float b2v[4];
#pragma unroll
  for (int n = 0; n < 4; ++n) b2v[n] = b2[s_ep + 16 * n];

  float* outU = out;
  float* outI = out + (size_t)NROWS * 64;
  float* outS = out + (size_t)NROWS * 64 + (size_t)NROWS * 3;

#pragma unroll
  for (int ch = 0; ch < 4; ++ch) {
    if (wr == (ch >> 1)) {
#pragma unroll
      for (int mm = 0; mm < 2; ++mm) {
        const int m = (ch & 1) * 2 + mm;
#pragma unroll
        for (int nf = 0; nf < 4; ++nf) {
#pragma unroll
          for (int q = 0; q < 4; ++q) {
            float z = acc[m][nf][q] * (1.0f / 1024.0f) + b1v[nf];
            float hs = gelu_exact(z) * 32.0f;
            _Float16 hi = (_Float16)hs;
            _Float16 lo = (_Float16)(hs - (float)hi);
            int rl = mm * 16 + lg * 4 + q;
            int cj = wc * 64 + nf * 16 + lr;
            int off = rl * 512 + (((cj >> 3) ^ (rl & 7)) * 16) + (cj & 7) * 2;
            *(_Float16*)(smem + H_H + off) = hi;
            *(_Float16*)(smem + H_L + off) = lo;
          }
        }
      }
    }
    __syncthreads();
    floatx4 acc2[2] = {z4, z4};
#pragma unroll
    for (int mf = 0; mf < 2; ++mf) {
      int rl = mf * 16 + lr;
#pragma unroll
      for (int ks = 0; ks < 4; ++ks) {
        int g = wr * 16 + ks * 4 + lg;
        int off = rl * 512 + ((g ^ (rl & 7)) * 16);
        half8 ha = *(half8*)(smem + H_H + off);
        half8 la = *(half8*)(smem + H_L + off);
        acc2[mf] = __builtin_amdgcn_mfma_f32_16x16x32_f16(ha, w2h[ks], acc2[mf], 0, 0, 0);
        acc2[mf] = __builtin_amdgcn_mfma_f32_16x16x32_f16(ha, w2l[ks], acc2[mf], 0, 0, 0);
        acc2[mf] = __builtin_amdgcn_mfma_f32_16x16x32_f16(la, w2h[ks], acc2[mf], 0, 0, 0);
      }
    }
    if (w >= 4) {
#pragma unroll
      for (int mf = 0; mf < 2; ++mf)
#pragma unroll
        for (int q = 0; q < 4; ++q) {
          int rp = mf * 16 + lg * 4 + q;
          int cp = wc * 16 + lr;
          *(float*)(smem + P_F + (rp * 64 + cp) * 4) = acc2[mf][q];
        }
    }
    __syncthreads();
    if (w < 4) {
#pragma unroll
      for (int mf = 0; mf < 2; ++mf)
#pragma unroll
        for (int q = 0; q < 4; ++q) {
          int rp = mf * 16 + lg * 4 + q;
          int cp = wc * 16 + lr;
          float* p = (float*)(smem + P_F + (rp * 64 + cp) * 4);
          *p = *p + acc2[mf][q];
        }
    }
    __syncthreads();
    {
      int rowg = row0 + ch * 32 + r_ep;
      float vals[4];
#pragma unroll
      for (int n = 0; n < 4; ++n)
        vals[n] = (*(float*)(smem + P_F + (r_ep * 64 + s_ep + 16 * n) * 4)) * (1.0f / 2048.0f) + b2v[n];

      float m1 = fmaxf(fmaxf(vals[0], vals[1]), fmaxf(vals[2], vals[3]));
#pragma unroll
      for (int d = 1; d < 16; d <<= 1) m1 = fmaxf(m1, __shfl_xor(m1, d));
      float e[4], ss = 0.f;
#pragma unroll
      for (int n = 0; n < 4; ++n) { e[n] = __expf(vals[n] - m1); ss += e[n]; }
#pragma unroll
      for (int d = 1; d < 16; d <<= 1) ss += __shfl_xor(ss, d);
      float inv = 1.0f / ss;
      float ps[4];
#pragma unroll
      for (int n = 0; n < 4; ++n) {
        ps[n] = e[n] * inv;
        outS[(size_t)rowg * 64 + s_ep + 16 * n] = ps[n];
      }
      float cur[4] = {vals[0], vals[1], vals[2], vals[3]};
      float tv[4]; int tc[4];
#pragma unroll
      for (int t = 0; t < 4; ++t) {
        float bv = -3.0e38f; int bc = 1 << 20;
#pragma unroll
        for (int n = 0; n < 4; ++n)
          if (cur[n] > bv) { bv = cur[n]; bc = s_ep + 16 * n; }
#pragma unroll
        for (int d = 1; d < 16; d <<= 1) {
          float ov = __shfl_xor(bv, d);
          int  oc = __shfl_xor(bc, d);
          if (ov > bv || (ov == bv && oc < bc)) { bv = ov; bc = oc; }
        }
        tv[t] = bv; tc[t] = bc;
#pragma unroll
        for (int n = 0; n < 4; ++n) if (s_ep + 16 * n == bc) cur[n] = -3.0e38f;
      }
      float l2[4];
#pragma unroll
      for (int n = 0; n < 4; ++n) {
        float p = fmaxf(ps[n], 1e-12f);
        float p2 = p * p;
        float p4 = p2 * p2;
        float lgv = logf(p4 + 1e-12f);
        int c = s_ep + 16 * n;
        bool top = (c == tc[0]) | (c == tc[1]) | (c == tc[2]);
        l2[n] = 10.0f * lgv + (top ? 0.0f : -46.051701859880914f);
      }
      float m2 = fmaxf(fmaxf(l2[0], l2[1]), fmaxf(l2[2], l2[3]));
#pragma unroll
      for (int d = 1; d < 16; d <<= 1) m2 = fmaxf(m2, __shfl_xor(m2, d));
      float e2[4], s2 = 0.f;
#pragma unroll
      for (int n = 0; n < 4; ++n) { e2[n] = __expf(l2[n] - m2); s2 += e2[n]; }
#pragma unroll
      for (int d = 1; d < 16; d <<= 1) s2 += __shfl_xor(s2, d);
      float inv2 = 1.0f / s2;
#pragma unroll
      for (int n = 0; n < 4; ++n) outU[(size_t)rowg * 64 + s_ep + 16 * n] = e2[n] * inv2;

      if (s_ep == 0) {
        outI[(size_t)rowg * 3 + 0] = (float)tc[0];
        outI[(size_t)rowg * 3 + 1] = (float)tc[1];
        outI[(size_t)rowg * 3 + 2] = (float)tc[2];
        float mg = fminf(tv[0] - tv[1], fminf(tv[1] - tv[2], tv[2] - tv[3]));
        if (mg < TAU && cap > 0) {
          int pos = atomicAdd(cnt, 1);
          if (pos < cap) list[pos] = rowg;
        }
      }
    }
    __syncthreads();
  }
}

// fp64 refinement of near-tie rows: recompute logits exactly, overwrite idx.
__global__ __launch_bounds__(256, 4) void router_refine(
    const float* __restrict__ feat, const float* __restrict__ W1,
    const float* __restrict__ b1, const float* __restrict__ W2,
    const float* __restrict__ b2, float* __restrict__ out,
    const int* __restrict__ cnt, const int* __restrict__ list, int cap)
{
  __shared__ float  fbuf[4][1024];
  __shared__ double hbuf[4][256];
  int n = *cnt; if (n > cap) n = cap;
  if (n <= 0) return;
  const int tid = threadIdx.x;
  const int wv = tid >> 6;
  const int l  = tid & 63;
  float* outI = out + (size_t)NROWS * 64;
#pragma unroll 1
  for (int base = blockIdx.x * 4; base < n; base += 4096) {
    int nrows = n - base; if (nrows > 4) nrows = 4;
    for (int rr = 0; rr < 4; ++rr) {
      if (rr < nrows) {
        int row = list[base + rr];
        for (int i = tid; i < 1024; i += 256) fbuf[rr][i] = feat[(size_t)row * 1024 + i];
      }
    }
    __syncthreads();
    if (wv < nrows) {
      double zq0 = 0, zq1 = 0, zq2 = 0, zq3 = 0;
#pragma unroll 4
      for (int i = 0; i < 1024; ++i) {
        double f = (double)fbuf[wv][i];
        const float* wrow = W1 + (size_t)i * 256 + l;
        zq0 += f * (double)wrow[0];
        zq1 += f * (double)wrow[64];
        zq2 += f * (double)wrow[128];
        zq3 += f * (double)wrow[192];
      }
      double zz[4] = {zq0 + (double)b1[l],       zq1 + (double)b1[l + 64],
                      zq2 + (double)b1[l + 128], zq3 + (double)b1[l + 192]};
#pragma unroll
      for (int q = 0; q < 4; ++q) {
        double z = zz[q];
        hbuf[wv][l + 64 * q] = 0.5 * z * (1.0 + erf(z * 0.70710678118654752440));
      }
    }
    __syncthreads();
    if (wv < nrows) {
      double lgt = (double)b2[l];
#pragma unroll 4
      for (int j = 0; j < 256; ++j) lgt += hbuf[wv][j] * (double)W2[(size_t)j * 64 + l];
      int chosen[3];
      double curv = lgt;
      for (int t = 0; t < 3; ++t) {
        double mv = curv; int mc = l;
        for (int d = 1; d < 64; d <<= 1) {
          double ov = __shfl_xor(mv, d);
          int   oc = __shfl_xor(mc, d);
          if (ov > mv || (ov == mv && oc < mc)) { mv = ov; mc = oc; }
        }
        chosen[t] = mc;
        if (l == mc) curv = -1.0e300;
      }
      if (l == 0) {
        int row = list[base + wv];
        outI[(size_t)row * 3 + 0] = (float)chosen[0];
        outI[(size_t)row * 3 + 1] = (float)chosen[1];
        outI[(size_t)row * 3 + 2] = (float)chosen[2];
      }
    }
    __syncthreads();
  }
}

extern "C" void kernel_launch(void* const* d_in, const int* in_sizes, int n_in,
                              void* d_out, int out_size, void* d_ws, size_t ws_size,
                              hipStream_t stream) {
  (void)in_sizes; (void)n_in; (void)out_size;
  const float* feat = (const float*)d_in[0];
  const float* W1   = (const float*)d_in[1];
  const float* b1   = (const float*)d_in[2];
  const float* W2   = (const float*)d_in[3];
  const float* b2   = (const float*)d_in[4];
  float* out = (float*)d_out;

  size_t need_fused = (size_t)W1S_BYTES + 4 + 16384;
  size_t need_split = (size_t)W1S_BYTES + H_BYTES + 4 + 16384;

  if (ws_size >= need_split) {
    unsigned char* w1s = (unsigned char*)d_ws;
    float* hbuf = (float*)(w1s + W1S_BYTES);
    int* cnt  = (int*)((unsigned char*)d_ws + W1S_BYTES + H_BYTES);
    int* list = cnt + 1;
    long capl = (long)((ws_size - W1S_BYTES - H_BYTES - 4) / 4);
    int cap = capl > 65536 ? 65536 : (int)capl;
    hipLaunchKernelGGL(router_prep, dim3(128), dim3(256), 0, stream, W1, w1s, cnt);
    hipLaunchKernelGGL(router_gemm1, dim3(NROWS / BM1), dim3(1024), 0, stream,
                       feat, w1s, b1, hbuf);
    hipLaunchKernelGGL(router_gemm2, dim3(NROWS / 32), dim3(512), 0, stream,
                       hbuf, W2, b2, out, cnt, list, cap);
    hipLaunchKernelGGL(router_refine, dim3(1024), dim3(256), 0, stream,
                       feat, W1, b1, W2, b2, out, cnt, list, cap);
  } else if (ws_size >= need_fused) {
    unsigned char* w1s = (unsigned char*)d_ws;
    int* cnt  = (int*)(w1s + W1S_BYTES);
    int* list = cnt + 1;
    long capl = (long)((ws_size - W1S_BYTES - 4) / 4);
    int cap = capl > 65536 ? 65536 : (int)capl;
    hipLaunchKernelGGL(router_prep, dim3(128), dim3(256), 0, stream, W1, w1s, cnt);
    hipLaunchKernelGGL(router_fused, dim3(NROWS / 128), dim3(512), 0, stream,
                       feat, w1s, b1, W2, b2, out, cnt, list, cap);
    hipLaunchKernelGGL(router_refine, dim3(1024), dim3(256), 0, stream,
                       feat, W1, b1, W2, b2, out, cnt, list, cap);
  } else {
    int* cnt  = (int*)d_ws;
    int* list = cnt + 1;
    long capl = (ws_size >= 8) ? (long)(ws_size / 4) - 1 : 0;
    int cap = capl < 0 ? 0 : (capl > 65536 ? 65536 : (int)capl);
    if (cap > 0) hipMemsetAsync(cnt, 0, sizeof(int), stream);
    hipLaunchKernelGGL(router_main_legacy, dim3(NROWS / 128), dim3(512), 0, stream,
                       feat, W1, b1, W2, b2, out, cnt, list, cap);
    if (cap > 0)
      hipLaunchKernelGGL(router_refine, dim3(1024), dim3(256), 0, stream,
                         feat, W1, b1, W2, b2, out, cnt, list, cap);
  }
}

// Round 13
// 444.537 us; speedup vs baseline: 1.0923x; 1.0021x over previous
//
#include <hip/hip_runtime.h>
#include <math.h>

typedef _Float16 half8 __attribute__((ext_vector_type(8)));
typedef _Float16 half4 __attribute__((ext_vector_type(4)));
typedef float floatx4 __attribute__((ext_vector_type(4)));

#define NROWS 131072
#define BM1 128
#define W1S_BYTES (32 * 32768)
#define H_BYTES ((size_t)NROWS * 256 * 4)

// ---- gemm1 / fused LDS map (96 KiB): double-buffered A and B (r6 layout) ----
#define A0b 0
#define A1b 16384
#define B0b 32768
#define B1b 65536
// ---- phase-2 map: H: [32][512B] per plane (XOR-swizzled); P: [32][64] f32
#define H_H 0
#define H_L 16384
#define P_F 32768

#define TAU 1e-4f

__device__ __forceinline__ float gelu_exact(float z) {
  return 0.5f * z * (1.0f + erff(z * 0.70710678118654752f));
}

// Pre-split W1 (scale 64) into per-k-tile images laid out byte-identically to
// the LDS B-tile; also zeroes the tie-list counter.
__global__ __launch_bounds__(256) void router_prep(const float* __restrict__ W1,
                                                   unsigned char* __restrict__ w1s,
                                                   int* __restrict__ cnt) {
  if (blockIdx.x == 0 && threadIdx.x == 0) *cnt = 0;
  int p = blockIdx.x * 256 + threadIdx.x;
  int col = p & 255;
  int g   = (p >> 8) & 3;
  int kt  = p >> 10;
  half8 hh, hl;
#pragma unroll
  for (int e = 0; e < 8; ++e) {
    float v = W1[(size_t)(kt * 32 + g * 8 + e) * 256 + col] * 64.0f;
    _Float16 h = (_Float16)v;
    hh[e] = h;
    hl[e] = (_Float16)(v - (float)h);
  }
  int off = col * 64 + ((g + (col >> 1)) & 3) * 16;
  unsigned char* base = w1s + (size_t)kt * 32768;
  *(half8*)(base + off) = hh;
  *(half8*)(base + 16384 + off) = hl;
}

// ---------------- 512-thread macros (fused fallback; r9-proven) ------------
#define GLDS_B(KT, BB) do {                                                  \
    const unsigned char* gp_ = w1s + (size_t)(KT) * 32768 + tid * 16;        \
    _Pragma("unroll") for (int j_ = 0; j_ < 4; ++j_) {                       \
      __builtin_amdgcn_global_load_lds(                                      \
        (const __attribute__((address_space(1))) void*)(gp_ + j_ * 8192),    \
        (__attribute__((address_space(3))) void*)(smem + (BB) + (w << 10) + j_ * 8192), \
        16, 0, 0);                                                           \
    }                                                                        \
  } while (0)

#define LOAD_A(KT, A0, A1) do {                                              \
    const float* ap_ = aptr + (KT) * 32;                                     \
    A0 = *(const float4*)(ap_);                                              \
    A1 = *(const float4*)(ap_ + 4);                                          \
  } while (0)

#define STAGE_A(A0, A1, AB) do {                                             \
    float av_[8] = {A0.x, A0.y, A0.z, A0.w, A1.x, A1.y, A1.z, A1.w};         \
    half8 hh_, hl_;                                                          \
    _Pragma("unroll") for (int e_ = 0; e_ < 8; ++e_) {                       \
      float x_ = av_[e_] * 16.0f;                                            \
      _Float16 h_ = (_Float16)x_;                                            \
      hh_[e_] = h_;                                                          \
      hl_[e_] = (_Float16)(x_ - (float)h_);                                  \
    }                                                                        \
    *(half8*)(smem + (AB) + awo)        = hh_;                               \
    *(half8*)(smem + (AB) + awo + 8192) = hl_;                               \
  } while (0)

#define MFMA_STEP(AB, BB) do {                                               \
    half8 bfh_[4], bfl_[4];                                                  \
    _Pragma("unroll") for (int nf_ = 0; nf_ < 4; ++nf_) {                    \
      int c_ = wc * 64 + nf_ * 16 + lr;                                      \
      int off_ = c_ * 64 + ((lg + (c_ >> 1)) & 3) * 16;                      \
      bfh_[nf_] = *(half8*)(smem + (BB) + off_);                             \
      bfl_[nf_] = *(half8*)(smem + (BB) + 16384 + off_);                     \
    }                                                                        \
    _Pragma("unroll") for (int mf_ = 0; mf_ < 4; ++mf_) {                    \
      int r_ = wr * 64 + mf_ * 16 + lr;                                      \
      int off_ = r_ * 64 + ((lg + (r_ >> 1)) & 3) * 16;                      \
      half8 ah_  = *(half8*)(smem + (AB) + off_);                            \
      half8 al_  = *(half8*)(smem + (AB) + 8192 + off_);                     \
      _Pragma("unroll") for (int nf_ = 0; nf_ < 4; ++nf_) {                  \
        acc[mf_][nf_] = __builtin_amdgcn_mfma_f32_16x16x32_f16(ah_, bfh_[nf_], acc[mf_][nf_], 0, 0, 0); \
        acc[mf_][nf_] = __builtin_amdgcn_mfma_f32_16x16x32_f16(ah_, bfl_[nf_], acc[mf_][nf_], 0, 0, 0); \
        acc[mf_][nf_] = __builtin_amdgcn_mfma_f32_16x16x32_f16(al_, bfh_[nf_], acc[mf_][nf_], 0, 0, 0); \
      }                                                                      \
    }                                                                        \
  } while (0)

// ---------------- 1024-thread macros (gemm1; 16 waves, acc[4][2]) ----------
#define GLDS_B16(KT, BB) do {                                                \
    const unsigned char* gp_ = w1s + (size_t)(KT) * 32768 + tid * 16;        \
    _Pragma("unroll") for (int j_ = 0; j_ < 2; ++j_) {                       \
      __builtin_amdgcn_global_load_lds(                                      \
        (const __attribute__((address_space(1))) void*)(gp_ + j_ * 16384),   \
        (__attribute__((address_space(3))) void*)(smem + (BB) + (w << 10) + j_ * 16384), \
        16, 0, 0);                                                           \
    }                                                                        \
  } while (0)

#define LOAD_A16(KT, A0) do {                                                \
    A0 = *(const float4*)(aptr + (KT) * 32);                                 \
  } while (0)

#define STAGE_A16(A0, AB) do {                                               \
    float av_[4] = {A0.x, A0.y, A0.z, A0.w};                                 \
    half4 hh_, hl_;                                                          \
    _Pragma("unroll") for (int e_ = 0; e_ < 4; ++e_) {                       \
      float x_ = av_[e_] * 16.0f;                                            \
      _Float16 h_ = (_Float16)x_;                                            \
      hh_[e_] = h_;                                                          \
      hl_[e_] = (_Float16)(x_ - (float)h_);                                  \
    }                                                                        \
    *(half4*)(smem + (AB) + awo)        = hh_;                               \
    *(half4*)(smem + (AB) + awo + 8192) = hl_;                               \
  } while (0)

#define MFMA_STEP16(AB, BB) do {                                             \
    half8 bfh_[2], bfl_[2];                                                  \
    _Pragma("unroll") for (int nf_ = 0; nf_ < 2; ++nf_) {                    \
      int c_ = wc8 * 32 + nf_ * 16 + lr;                                     \
      int off_ = c_ * 64 + ((lg + (c_ >> 1)) & 3) * 16;                      \
      bfh_[nf_] = *(half8*)(smem + (BB) + off_);                             \
      bfl_[nf_] = *(half8*)(smem + (BB) + 16384 + off_);                     \
    }                                                                        \
    _Pragma("unroll") for (int mf_ = 0; mf_ < 4; ++mf_) {                    \
      int r_ = wr * 64 + mf_ * 16 + lr;                                      \
      int off_ = r_ * 64 + ((lg + (r_ >> 1)) & 3) * 16;                      \
      half8 ah_  = *(half8*)(smem + (AB) + off_);                            \
      half8 al_  = *(half8*)(smem + (AB) + 8192 + off_);                     \
      _Pragma("unroll") for (int nf_ = 0; nf_ < 2; ++nf_) {                  \
        acc[mf_][nf_] = __builtin_amdgcn_mfma_f32_16x16x32_f16(ah_, bfh_[nf_], acc[mf_][nf_], 0, 0, 0); \
        acc[mf_][nf_] = __builtin_amdgcn_mfma_f32_16x16x32_f16(ah_, bfl_[nf_], acc[mf_][nf_], 0, 0, 0); \
        acc[mf_][nf_] = __builtin_amdgcn_mfma_f32_16x16x32_f16(al_, bfh_[nf_], acc[mf_][nf_], 0, 0, 0); \
      }                                                                      \
    }                                                                        \
  } while (0)

// ================= GEMM1: h = gelu(feat @ W1 + b1) -> ws (f32) =============
// r12 champion: 1024 threads (16 waves = 4 waves/SIMD), BM=128.
__global__ __launch_bounds__(1024, 4) void router_gemm1(
    const float* __restrict__ feat, const unsigned char* __restrict__ w1s,
    const float* __restrict__ b1, float* __restrict__ hbuf)
{
  __shared__ __align__(16) unsigned char smem[98304];
  const int tid = threadIdx.x;
  const int w  = tid >> 6;     // wave 0..15
  const int l  = tid & 63;
  const int lr = l & 15;
  const int lg = l >> 4;
  const int wr  = w >> 3;      // 0..1 : row half
  const int wc8 = w & 7;       // 0..7 : col eighth (32 cols)
  const int row0 = blockIdx.x * BM1;

  floatx4 acc[4][2];           // 32 AGPRs; compile-time indexed only
  const floatx4 z4 = {0.f, 0.f, 0.f, 0.f};
#pragma unroll
  for (int m = 0; m < 4; ++m)
#pragma unroll
    for (int n = 0; n < 2; ++n) acc[m][n] = z4;

  // A staging: 128 rows x 32 k floats = 4096 = 1024 threads x 1 float4
  const int arow = tid >> 3;          // 0..127
  const int ag   = (tid >> 1) & 3;    // granule 0..3
  const int ahf  = tid & 1;           // 16B half of the 32B granule slot
  const float* aptr = feat + (size_t)(row0 + arow) * 1024 + ag * 8 + ahf * 4;
  const int awo = arow * 64 + ((ag + (arow >> 1)) & 3) * 16 + ahf * 8;

  float4 aE0, aO0;

  GLDS_B16(0, B0b);
  LOAD_A16(0, aE0);
  LOAD_A16(1, aO0);
  STAGE_A16(aE0, A0b);
  __syncthreads();

#pragma unroll 1
  for (int kt = 0; kt < 32; kt += 2) {
    GLDS_B16(kt + 1, B1b);
    if (kt + 2 < 32) LOAD_A16(kt + 2, aE0);
    STAGE_A16(aO0, A1b);
    MFMA_STEP16(A0b, B0b);
    __syncthreads();
    if (kt + 2 < 32) {
      GLDS_B16(kt + 2, B0b);
      STAGE_A16(aE0, A0b);
    }
    if (kt + 3 < 32) LOAD_A16(kt + 3, aO0);
    MFMA_STEP16(A1b, B1b);
    __syncthreads();
  }

  // epilogue: h = gelu(z) -> global f32 (exact; same values as fused path)
  float b1v[2];
#pragma unroll
  for (int n = 0; n < 2; ++n) b1v[n] = b1[wc8 * 32 + n * 16 + lr];
#pragma unroll
  for (int m = 0; m < 4; ++m)
#pragma unroll
    for (int nf = 0; nf < 2; ++nf)
#pragma unroll
      for (int q = 0; q < 4; ++q) {
        float z = acc[m][nf][q] * (1.0f / 1024.0f) + b1v[nf];
        float hv = gelu_exact(z);
        int r = wr * 64 + m * 16 + lg * 4 + q;
        int c = wc8 * 32 + nf * 16 + lr;
        hbuf[(size_t)(row0 + r) * 256 + c] = hv;
      }
}

// ================= GEMM2: logits/softmax/topk from h =======================
// 64 rows per block (2 chunks of 32): W2 fragments + b2 loaded ONCE per
// block and amortized over 2x rows; per-chunk math byte-identical to r9.
__global__ __launch_bounds__(512, 4) void router_gemm2(
    const float* __restrict__ hbuf, const float* __restrict__ W2,
    const float* __restrict__ b2, float* __restrict__ out,
    int* __restrict__ cnt, int* __restrict__ list, int cap)
{
  __shared__ __align__(16) unsigned char smem[40960];
  const int tid = threadIdx.x;
  const int w  = tid >> 6;
  const int l  = tid & 63;
  const int lr = l & 15;
  const int lg = l >> 4;
  const int wr = w >> 2;     // k half
  const int wc = w & 3;      // col frag
  const int row0 = blockIdx.x * 64;
  const floatx4 z4 = {0.f, 0.f, 0.f, 0.f};

  half8 w2h[4], w2l[4];
#pragma unroll
  for (int ks = 0; ks < 4; ++ks)
#pragma unroll
    for (int jj = 0; jj < 8; ++jj) {
      int j = wr * 128 + ks * 32 + lg * 8 + jj;
      float v = W2[(size_t)j * 64 + wc * 16 + lr] * 64.0f;
      _Float16 h = (_Float16)v;
      w2h[ks][jj] = h;
      w2l[ks][jj] = (_Float16)(v - (float)h);
    }
  const int s_ep = tid & 15;
  const int r_ep = tid >> 4;   // 0..31
  float b2v[4];
#pragma unroll
  for (int n = 0; n < 4; ++n) b2v[n] = b2[s_ep + 16 * n];

  float* outU = out;
  float* outI = out + (size_t)NROWS * 64;
  float* outS = out + (size_t)NROWS * 64 + (size_t)NROWS * 3;

#pragma unroll
  for (int ch = 0; ch < 2; ++ch) {
    const int rbase = row0 + ch * 32;
    // stage h rows (scale 32, split f16) into XOR-swizzled LDS
    {
      const int hr  = tid >> 4;         // 0..31
      const int hc0 = (tid & 15) * 16;  // 16 cols per thread
      const float* hp = hbuf + (size_t)(rbase + hr) * 256 + hc0;
      float4 hv0 = *(const float4*)(hp);
      float4 hv1 = *(const float4*)(hp + 4);
      float4 hv2 = *(const float4*)(hp + 8);
      float4 hv3 = *(const float4*)(hp + 12);
      float hvs[16] = {hv0.x, hv0.y, hv0.z, hv0.w, hv1.x, hv1.y, hv1.z, hv1.w,
                       hv2.x, hv2.y, hv2.z, hv2.w, hv3.x, hv3.y, hv3.z, hv3.w};
#pragma unroll
      for (int j = 0; j < 16; ++j) {
        float hs = hvs[j] * 32.0f;
        _Float16 hi = (_Float16)hs;
        _Float16 lo = (_Float16)(hs - (float)hi);
        int cj = hc0 + j;
        int off = hr * 512 + (((cj >> 3) ^ (hr & 7)) * 16) + (cj & 7) * 2;
        *(_Float16*)(smem + H_H + off) = hi;
        *(_Float16*)(smem + H_L + off) = lo;
      }
    }
    __syncthreads();

    floatx4 acc2[2] = {z4, z4};
#pragma unroll
    for (int mf = 0; mf < 2; ++mf) {
      int rl = mf * 16 + lr;
#pragma unroll
      for (int ks = 0; ks < 4; ++ks) {
        int g = wr * 16 + ks * 4 + lg;
        int off = rl * 512 + ((g ^ (rl & 7)) * 16);
        half8 ha = *(half8*)(smem + H_H + off);
        half8 la = *(half8*)(smem + H_L + off);
        acc2[mf] = __builtin_amdgcn_mfma_f32_16x16x32_f16(ha, w2h[ks], acc2[mf], 0, 0, 0);
        acc2[mf] = __builtin_amdgcn_mfma_f32_16x16x32_f16(ha, w2l[ks], acc2[mf], 0, 0, 0);
        acc2[mf] = __builtin_amdgcn_mfma_f32_16x16x32_f16(la, w2h[ks], acc2[mf], 0, 0, 0);
      }
    }
    // combine the two k-halves through LDS
    if (w >= 4) {
#pragma unroll
      for (int mf = 0; mf < 2; ++mf)
#pragma unroll
        for (int q = 0; q < 4; ++q) {
          int rp = mf * 16 + lg * 4 + q;
          int cp = wc * 16 + lr;
          *(float*)(smem + P_F + (rp * 64 + cp) * 4) = acc2[mf][q];
        }
    }
    __syncthreads();
    if (w < 4) {
#pragma unroll
      for (int mf = 0; mf < 2; ++mf)
#pragma unroll
        for (int q = 0; q < 4; ++q) {
          int rp = mf * 16 + lg * 4 + q;
          int cp = wc * 16 + lr;
          float* p = (float*)(smem + P_F + (rp * 64 + cp) * 4);
          *p = *p + acc2[mf][q];
        }
    }
    __syncthreads();

    // epilogue: 16 threads per row, 4 cols each
    {
      int rowg = rbase + r_ep;
      float vals[4];
#pragma unroll
      for (int n = 0; n < 4; ++n)
        vals[n] = (*(float*)(smem + P_F + (r_ep * 64 + s_ep + 16 * n) * 4)) * (1.0f / 2048.0f) + b2v[n];

      float m1 = fmaxf(fmaxf(vals[0], vals[1]), fmaxf(vals[2], vals[3]));
#pragma unroll
      for (int d = 1; d < 16; d <<= 1) m1 = fmaxf(m1, __shfl_xor(m1, d));
      float e[4], ss = 0.f;
#pragma unroll
      for (int n = 0; n < 4; ++n) { e[n] = __expf(vals[n] - m1); ss += e[n]; }
#pragma unroll
      for (int d = 1; d < 16; d <<= 1) ss += __shfl_xor(ss, d);
      float inv = 1.0f / ss;
      float ps[4];
#pragma unroll
      for (int n = 0; n < 4; ++n) {
        ps[n] = e[n] * inv;
        outS[(size_t)rowg * 64 + s_ep + 16 * n] = ps[n];
      }
      float cur[4] = {vals[0], vals[1], vals[2], vals[3]};
      float tv[4]; int tc[4];
#pragma unroll
      for (int t = 0; t < 4; ++t) {
        float bv = -3.0e38f; int bc = 1 << 20;
#pragma unroll
        for (int n = 0; n < 4; ++n)
          if (cur[n] > bv) { bv = cur[n]; bc = s_ep + 16 * n; }
#pragma unroll
        for (int d = 1; d < 16; d <<= 1) {
          float ov = __shfl_xor(bv, d);
          int  oc = __shfl_xor(bc, d);
          if (ov > bv || (ov == bv && oc < bc)) { bv = ov; bc = oc; }
        }
        tv[t] = bv; tc[t] = bc;
#pragma unroll
        for (int n = 0; n < 4; ++n) if (s_ep + 16 * n == bc) cur[n] = -3.0e38f;
      }
      float l2[4];
#pragma unroll
      for (int n = 0; n < 4; ++n) {
        float p = fmaxf(ps[n], 1e-12f);
        float p2 = p * p;
        float p4 = p2 * p2;
        float lgv = logf(p4 + 1e-12f);
        int c = s_ep + 16 * n;
        bool top = (c == tc[0]) | (c == tc[1]) | (c == tc[2]);
        l2[n] = 10.0f * lgv + (top ? 0.0f : -46.051701859880914f);
      }
      float m2 = fmaxf(fmaxf(l2[0], l2[1]), fmaxf(l2[2], l2[3]));
#pragma unroll
      for (int d = 1; d < 16; d <<= 1) m2 = fmaxf(m2, __shfl_xor(m2, d));
      float e2[4], s2 = 0.f;
#pragma unroll
      for (int n = 0; n < 4; ++n) { e2[n] = __expf(l2[n] - m2); s2 += e2[n]; }
#pragma unroll
      for (int d = 1; d < 16; d <<= 1) s2 += __shfl_xor(s2, d);
      float inv2 = 1.0f / s2;
#pragma unroll
      for (int n = 0; n < 4; ++n) outU[(size_t)rowg * 64 + s_ep + 16 * n] = e2[n] * inv2;

      if (s_ep == 0) {
        outI[(size_t)rowg * 3 + 0] = (float)tc[0];
        outI[(size_t)rowg * 3 + 1] = (float)tc[1];
        outI[(size_t)rowg * 3 + 2] = (float)tc[2];
        float mg = fminf(tv[0] - tv[1], fminf(tv[1] - tv[2], tv[2] - tv[3]));
        if (mg < TAU && cap > 0) {
          int pos = atomicAdd(cnt, 1);
          if (pos < cap) list[pos] = rowg;
        }
      }
    }
    __syncthreads();
  }
}

// ================= fused fallback (r6 winner, BM=128, __syncthreads) =======
__global__ __launch_bounds__(512, 2) void router_fused(
    const float* __restrict__ feat, const unsigned char* __restrict__ w1s,
    const float* __restrict__ b1, const float* __restrict__ W2,
    const float* __restrict__ b2, float* __restrict__ out,
    int* __restrict__ cnt, int* __restrict__ list, int cap)
{
  __shared__ __align__(16) unsigned char smem[98304];
  const int tid = threadIdx.x;
  const int w  = tid >> 6;
  const int l  = tid & 63;
  const int lr = l & 15;
  const int lg = l >> 4;
  const int wr = w >> 2;
  const int wc = w & 3;
  const int row0 = blockIdx.x * 128;

  floatx4 acc[4][4];
  const floatx4 z4 = {0.f, 0.f, 0.f, 0.f};
#pragma unroll
  for (int m = 0; m < 4; ++m)
#pragma unroll
    for (int n = 0; n < 4; ++n) acc[m][n] = z4;

  const int arow = tid >> 2;
  const int aq   = tid & 3;
  const float* aptr = feat + (size_t)(row0 + arow) * 1024 + aq * 8;
  const int awo = arow * 64 + ((aq + (arow >> 1)) & 3) * 16;

  float4 aE0, aE1, aO0, aO1;

  GLDS_B(0, B0b);
  LOAD_A(0, aE0, aE1);
  LOAD_A(1, aO0, aO1);
  STAGE_A(aE0, aE1, A0b);
  __syncthreads();

#pragma unroll 1
  for (int kt = 0; kt < 32; kt += 2) {
    GLDS_B(kt + 1, B1b);
    if (kt + 2 < 32) LOAD_A(kt + 2, aE0, aE1);
    STAGE_A(aO0, aO1, A1b);
    MFMA_STEP(A0b, B0b);
    __syncthreads();
    if (kt + 2 < 32) {
      GLDS_B(kt + 2, B0b);
      STAGE_A(aE0, aE1, A0b);
    }
    if (kt + 3 < 32) LOAD_A(kt + 3, aO0, aO1);
    MFMA_STEP(A1b, B1b);
    __syncthreads();
  }

  half8 w2h[4], w2l[4];
#pragma unroll
  for (int ks = 0; ks < 4; ++ks)
#pragma unroll
    for (int jj = 0; jj < 8; ++jj) {
      int j = wr * 128 + ks * 32 + lg * 8 + jj;
      float v = W2[(size_t)j * 64 + wc * 16 + lr] * 64.0f;
      _Float16 h = (_Float16)v;
      w2h[ks][jj] = h;
      w2l[ks][jj] = (_Float16)(v - (float)h);
    }
  float b1v[4];
#pragma unroll
  for (int n = 0; n < 4; ++n) b1v[n] = b1[wc * 64 + n * 16 + lr];
  const int s_ep = tid & 15;
  const int r_ep = tid >> 4;
  float b2v[4];
#pragma unroll
  for (int n = 0; n < 4; ++n) b2v[n] = b2[s_ep + 16 * n];

  float* outU = out;
  float* outI = out + (size_t)NROWS * 64;
  float* outS = out + (size_t)NROWS * 64 + (size_t)NROWS * 3;

#pragma unroll
  for (int ch = 0; ch < 4; ++ch) {
    if (wr == (ch >> 1)) {
#pragma unroll
      for (int mm = 0; mm < 2; ++mm) {
        const int m = (ch & 1) * 2 + mm;
#pragma unroll
        for (int nf = 0; nf < 4; ++nf) {
#pragma unroll
          for (int q = 0; q < 4; ++q) {
            float z = acc[m][nf][q] * (1.0f / 1024.0f) + b1v[nf];
            float hs = gelu_exact(z) * 32.0f;
            _Float16 hi = (_Float16)hs;
            _Float16 lo = (_Float16)(hs - (float)hi);
            int rl = mm * 16 + lg * 4 + q;
            int cj = wc * 64 + nf * 16 + lr;
            int off = rl * 512 + (((cj >> 3) ^ (rl & 7)) * 16) + (cj & 7) * 2;
            *(_Float16*)(smem + H_H + off) = hi;
            *(_Float16*)(smem + H_L + off) = lo;
          }
        }
      }
    }
    __syncthreads();
    floatx4 acc2[2] = {z4, z4};
#pragma unroll
    for (int mf = 0; mf < 2; ++mf) {
      int rl = mf * 16 + lr;
#pragma unroll
      for (int ks = 0; ks < 4; ++ks) {
        int g = wr * 16 + ks * 4 + lg;
        int off = rl * 512 + ((g ^ (rl & 7)) * 16);
        half8 ha = *(half8*)(smem + H_H + off);
        half8 la = *(half8*)(smem + H_L + off);
        acc2[mf] = __builtin_amdgcn_mfma_f32_16x16x32_f16(ha, w2h[ks], acc2[mf], 0, 0, 0);
        acc2[mf] = __builtin_amdgcn_mfma_f32_16x16x32_f16(ha, w2l[ks], acc2[mf], 0, 0, 0);
        acc2[mf] = __builtin_amdgcn_mfma_f32_16x16x32_f16(la, w2h[ks], acc2[mf], 0, 0, 0);
      }
    }
    if (w >= 4) {
#pragma unroll
      for (int mf = 0; mf < 2; ++mf)
#pragma unroll
        for (int q = 0; q < 4; ++q) {
          int rp = mf * 16 + lg * 4 + q;
          int cp = wc * 16 + lr;
          *(float*)(smem + P_F + (rp * 64 + cp) * 4) = acc2[mf][q];
        }
    }
    __syncthreads();
    if (w < 4) {
#pragma unroll
      for (int mf = 0; mf < 2; ++mf)
#pragma unroll
        for (int q = 0; q < 4; ++q) {
          int rp = mf * 16 + lg * 4 + q;
          int cp = wc * 16 + lr;
          float* p = (float*)(smem + P_F + (rp * 64 + cp) * 4);
          *p = *p + acc2[mf][q];
        }
    }
    __syncthreads();
    {
      int rowg = row0 + ch * 32 + r_ep;
      float vals[4];
#pragma unroll
      for (int n = 0; n < 4; ++n)
        vals[n] = (*(float*)(smem + P_F + (r_ep * 64 + s_ep + 16 * n) * 4)) * (1.0f / 2048.0f) + b2v[n];

      float m1 = fmaxf(fmaxf(vals[0], vals[1]), fmaxf(vals[2], vals[3]));
#pragma unroll
      for (int d = 1; d < 16; d <<= 1) m1 = fmaxf(m1, __shfl_xor(m1, d));
      float e[4], ss = 0.f;
#pragma unroll
      for (int n = 0; n < 4; ++n) { e[n] = __expf(vals[n] - m1); ss += e[n]; }
#pragma unroll
      for (int d = 1; d < 16; d <<= 1) ss += __shfl_xor(ss, d);
      float inv = 1.0f / ss;
      float ps[4];
#pragma unroll
      for (int n = 0; n < 4; ++n) {
        ps[n] = e[n] * inv;
        outS[(size_t)rowg * 64 + s_ep + 16 * n] = ps[n];
      }
      float cur[4] = {vals[0], vals[1], vals[2], vals[3]};
      float tv[4]; int tc[4];
#pragma unroll
      for (int t = 0; t < 4; ++t) {
        float bv = -3.0e38f; int bc = 1 << 20;
#pragma unroll
        for (int n = 0; n < 4; ++n)
          if (cur[n] > bv) { bv = cur[n]; bc = s_ep + 16 * n; }
#pragma unroll
        for (int d = 1; d < 16; d <<= 1) {
          float ov = __shfl_xor(bv, d);
          int  oc = __shfl_xor(bc, d);
          if (ov > bv || (ov == bv && oc < bc)) { bv = ov; bc = oc; }
        }
        tv[t] = bv; tc[t] = bc;
#pragma unroll
        for (int n = 0; n < 4; ++n) if (s_ep + 16 * n == bc) cur[n] = -3.0e38f;
      }
      float l2[4];
#pragma unroll
      for (int n = 0; n < 4; ++n) {
        float p = fmaxf(ps[n], 1e-12f);
        float p2 = p * p;
        float p4 = p2 * p2;
        float lgv = logf(p4 + 1e-12f);
        int c = s_ep + 16 * n;
        bool top = (c == tc[0]) | (c == tc[1]) | (c == tc[2]);
        l2[n] = 10.0f * lgv + (top ? 0.0f : -46.051701859880914f);
      }
      float m2 = fmaxf(fmaxf(l2[0], l2[1]), fmaxf(l2[2], l2[3]));
#pragma unroll
      for (int d = 1; d < 16; d <<= 1) m2 = fmaxf(m2, __shfl_xor(m2, d));
      float e2[4], s2 = 0.f;
#pragma unroll
      for (int n = 0; n < 4; ++n) { e2[n] = __expf(l2[n] - m2); s2 += e2[n]; }
#pragma unroll
      for (int d = 1; d < 16; d <<= 1) s2 += __shfl_xor(s2, d);
      float inv2 = 1.0f / s2;
#pragma unroll
      for (int n = 0; n < 4; ++n) outU[(size_t)rowg * 64 + s_ep + 16 * n] = e2[n] * inv2;

      if (s_ep == 0) {
        outI[(size_t)rowg * 3 + 0] = (float)tc[0];
        outI[(size_t)rowg * 3 + 1] = (float)tc[1];
        outI[(size_t)rowg * 3 + 2] = (float)tc[2];
        float mg = fminf(tv[0] - tv[1], fminf(tv[1] - tv[2], tv[2] - tv[3]));
        if (mg < TAU && cap > 0) {
          int pos = atomicAdd(cnt, 1);
          if (pos < cap) list[pos] = rowg;
        }
      }
    }
    __syncthreads();
  }
}

// ---------------- legacy main kernel (no-workspace fallback) ----------------
__global__ __launch_bounds__(512, 2) void router_main_legacy(
    const float* __restrict__ feat, const float* __restrict__ W1,
    const float* __restrict__ b1, const float* __restrict__ W2,
    const float* __restrict__ b2, float* __restrict__ out,
    int* __restrict__ cnt, int* __restrict__ list, int cap)
{
  __shared__ __align__(16) unsigned char smem[49152];
  const int tid = threadIdx.x;
  const int w  = tid >> 6;
  const int l  = tid & 63;
  const int lr = l & 15;
  const int lg = l >> 4;
  const int wr = w >> 2;
  const int wc = w & 3;
  const int row0 = blockIdx.x * 128;

  floatx4 acc[4][4];
  const floatx4 z4 = {0.f, 0.f, 0.f, 0.f};
#pragma unroll
  for (int m = 0; m < 4; ++m)
#pragma unroll
    for (int n = 0; n < 4; ++n) acc[m][n] = z4;

  const int arow = tid >> 2;
  const int aq   = tid & 3;
  const int bcol = tid & 255;
  const int bh2  = tid >> 8;

  const float* aptr = feat + (size_t)(row0 + arow) * 1024 + aq * 8;
  const float* bptr = W1 + (size_t)(bh2 * 16) * 256 + bcol;

  const int L_AH = 0, L_AL = 8192, L_BH = 16384, L_BL = 32768;
  const int awo  = L_AH + arow * 64 + ((aq + (arow >> 1)) & 3) * 16;
  const int bg0  = bh2 * 2;
  const int bwo0 = L_BH + bcol * 64 + (((bg0    ) + (bcol >> 1)) & 3) * 16;
  const int bwo1 = L_BH + bcol * 64 + (((bg0 + 1) + (bcol >> 1)) & 3) * 16;

  float4 a0, a1;
  float pb[16];

  a0 = *(const float4*)(aptr);
  a1 = *(const float4*)(aptr + 4);
#pragma unroll
  for (int q = 0; q < 16; ++q) pb[q] = bptr[q * 256];

#pragma unroll 1
  for (int kt = 0; kt < 32; ++kt) {
    {
      float av[8] = {a0.x, a0.y, a0.z, a0.w, a1.x, a1.y, a1.z, a1.w};
      half8 hh, hl;
#pragma unroll
      for (int e = 0; e < 8; ++e) {
        float x = av[e] * 16.0f;
        _Float16 h = (_Float16)x;
        hh[e] = h;
        hl[e] = (_Float16)(x - (float)h);
      }
      *(half8*)(smem + awo)        = hh;
      *(half8*)(smem + awo + 8192) = hl;

      half8 c0h, c0l, c1h, c1l;
#pragma unroll
      for (int e = 0; e < 8; ++e) {
        float x = pb[e] * 64.0f;
        _Float16 h = (_Float16)x;
        c0h[e] = h; c0l[e] = (_Float16)(x - (float)h);
        float y = pb[e + 8] * 64.0f;
        _Float16 h2 = (_Float16)y;
        c1h[e] = h2; c1l[e] = (_Float16)(y - (float)h2);
      }
      *(half8*)(smem + bwo0)         = c0h;
      *(half8*)(smem + bwo0 + 16384) = c0l;
      *(half8*)(smem + bwo1)         = c1h;
      *(half8*)(smem + bwo1 + 16384) = c1l;
    }
    __syncthreads();
    if (kt + 1 < 32) {
      const float* ap = aptr + (kt + 1) * 32;
      a0 = *(const float4*)(ap);
      a1 = *(const float4*)(ap + 4);
      const float* bp = bptr + (size_t)(kt + 1) * 8192;
#pragma unroll
      for (int q = 0; q < 16; ++q) pb[q] = bp[q * 256];
    }
    {
      half8 bfh[4], bfl[4];
#pragma unroll
      for (int nf = 0; nf < 4; ++nf) {
        int c = wc * 64 + nf * 16 + lr;
        int off = c * 64 + ((lg + (c >> 1)) & 3) * 16;
        bfh[nf] = *(half8*)(smem + L_BH + off);
        bfl[nf] = *(half8*)(smem + L_BL + off);
      }
#pragma unroll
      for (int mf = 0; mf < 4; ++mf) {
        int r = wr * 64 + mf * 16 + lr;
        int off = r * 64 + ((lg + (r >> 1)) & 3) * 16;
        half8 ah  = *(half8*)(smem + L_AH + off);
        half8 al2 = *(half8*)(smem + L_AL + off);
#pragma unroll
        for (int nf = 0; nf < 4; ++nf) {
          acc[mf][nf] = __builtin_amdgcn_mfma_f32_16x16x32_f16(ah,  bfh[nf], acc[mf][nf], 0, 0, 0);
          acc[mf][nf] = __builtin_amdgcn_mfma_f32_16x16x32_f16(ah,  bfl[nf], acc[mf][nf], 0, 0, 0);
          acc[mf][nf] = __builtin_amdgcn_mfma_f32_16x16x32_f16(al2, bfh[nf], acc[mf][nf], 0, 0, 0);
        }
      }
    }
    __syncthreads();
  }

  half8 w2h[4], w2l[4];
#pragma unroll
  for (int ks = 0; ks < 4; ++ks)
#pragma unroll
    for (int jj = 0; jj < 8; ++jj) {
      int j = wr * 128 + ks * 32 + lg * 8 + jj;
      float v = W2[(size_t)j * 64 + wc * 16 + lr] * 64.0f;
      _Float16 h = (_Float16)v;
      w2h[ks][jj] = h;
      w2l[ks][jj] = (_Float16)(v - (float)h);
    }
  float b1v[4];
#pragma unroll
  for (int n = 0; n < 4; ++n) b1v[n] = b1[wc * 64 + n * 16 + lr];
  const int s_ep = tid & 15;
  const int r_ep = tid >> 4;
  float b2v[4];
#pragma unroll
  for (int n = 0; n < 4; ++n) b2v[n] = b2[s_ep + 16 * n];

  float* outU = out;
  float* outI = out + (size_t)NROWS * 64;
  float* outS = out + (size_t)NROWS * 64 + (size_t)NROWS * 3;

#pragma unroll
  for (int ch = 0; ch < 4; ++ch) {
    if (wr == (ch >> 1)) {
#pragma unroll
      for (int mm = 0; mm < 2; ++mm) {
        const int m = (ch & 1) * 2 + mm;
#pragma unroll
        for (int nf = 0; nf < 4; ++nf) {
#pragma unroll
          for (int q = 0; q < 4; ++q) {
            float z = acc[m][nf][q] * (1.0f / 1024.0f) + b1v[nf];
            float hs = gelu_exact(z) * 32.0f;
            _Float16 hi = (_Float16)hs;
            _Float16 lo = (_Float16)(hs - (float)hi);
            int rl = mm * 16 + lg * 4 + q;
            int cj = wc * 64 + nf * 16 + lr;
            int off = rl * 512 + (((cj >> 3) ^ (rl & 7)) * 16) + (cj & 7) * 2;
            *(_Float16*)(smem + H_H + off) = hi;
            *(_Float16*)(smem + H_L + off) = lo;
          }
        }
      }
    }
    __syncthreads();
    floatx4 acc2[2] = {z4, z4};
#pragma unroll
    for (int mf = 0; mf < 2; ++mf) {
      int rl = mf * 16 + lr;
#pragma unroll
      for (int ks = 0; ks < 4; ++ks) {
        int g = wr * 16 + ks * 4 + lg;
        int off = rl * 512 + ((g ^ (rl & 7)) * 16);
        half8 ha = *(half8*)(smem + H_H + off);
        half8 la = *(half8*)(smem + H_L + off);
        acc2[mf] = __builtin_amdgcn_mfma_f32_16x16x32_f16(ha, w2h[ks], acc2[mf], 0, 0, 0);
        acc2[mf] = __builtin_amdgcn_mfma_f32_16x16x32_f16(ha, w2l[ks], acc2[mf], 0, 0, 0);
        acc2[mf] = __builtin_amdgcn_mfma_f32_16x16x32_f16(la, w2h[ks], acc2[mf], 0, 0, 0);
      }
    }
    if (w >= 4) {
#pragma unroll
      for (int mf = 0; mf < 2; ++mf)
#pragma unroll
        for (int q = 0; q < 4; ++q) {
          int rp = mf * 16 + lg * 4 + q;
          int cp = wc * 16 + lr;
          *(float*)(smem + P_F + (rp * 64 + cp) * 4) = acc2[mf][q];
        }
    }
    __syncthreads();
    if (w < 4) {
#pragma unroll
      for (int mf = 0; mf < 2; ++mf)
#pragma unroll
        for (int q = 0; q < 4; ++q) {
          int rp = mf * 16 + lg * 4 + q;
          int cp = wc * 16 + lr;
          float* p = (float*)(smem + P_F + (rp * 64 + cp) * 4);
          *p = *p + acc2[mf][q];
        }
    }
    __syncthreads();
    {
      int rowg = row0 + ch * 32 + r_ep;
      float vals[4];
#pragma unroll
      for (int n = 0; n < 4; ++n)
        vals[n] = (*(float*)(smem + P_F + (r_ep * 64 + s_ep + 16 * n) * 4)) * (1.0f / 2048.0f) + b2v[n];

      float m1 = fmaxf(fmaxf(vals[0], vals[1]), fmaxf(vals[2], vals[3]));
#pragma unroll
      for (int d = 1; d < 16; d <<= 1) m1 = fmaxf(m1, __shfl_xor(m1, d));
      float e[4], ss = 0.f;
#pragma unroll
      for (int n = 0; n < 4; ++n) { e[n] = __expf(vals[n] - m1); ss += e[n]; }
#pragma unroll
      for (int d = 1; d < 16; d <<= 1) ss += __shfl_xor(ss, d);
      float inv = 1.0f / ss;
      float ps[4];
#pragma unroll
      for (int n = 0; n < 4; ++n) {
        ps[n] = e[n] * inv;
        outS[(size_t)rowg * 64 + s_ep + 16 * n] = ps[n];
      }
      float cur[4] = {vals[0], vals[1], vals[2], vals[3]};
      float tv[4]; int tc[4];
#pragma unroll
      for (int t = 0; t < 4; ++t) {
        float bv = -3.0e38f; int bc = 1 << 20;
#pragma unroll
        for (int n = 0; n < 4; ++n)
          if (cur[n] > bv) { bv = cur[n]; bc = s_ep + 16 * n; }
#pragma unroll
        for (int d = 1; d < 16; d <<= 1) {
          float ov = __shfl_xor(bv, d);
          int  oc = __shfl_xor(bc, d);
          if (ov > bv || (ov == bv && oc < bc)) { bv = ov; bc = oc; }
        }
        tv[t] = bv; tc[t] = bc;
#pragma unroll
        for (int n = 0; n < 4; ++n) if (s_ep + 16 * n == bc) cur[n] = -3.0e38f;
      }
      float l2[4];
#pragma unroll
      for (int n = 0; n < 4; ++n) {
        float p = fmaxf(ps[n], 1e-12f);
        float p2 = p * p;
        float p4 = p2 * p2;
        float lgv = logf(p4 + 1e-12f);
        int c = s_ep + 16 * n;
        bool top = (c == tc[0]) | (c == tc[1]) | (c == tc[2]);
        l2[n] = 10.0f * lgv + (top ? 0.0f : -46.051701859880914f);
      }
      float m2 = fmaxf(fmaxf(l2[0], l2[1]), fmaxf(l2[2], l2[3]));
#pragma unroll
      for (int d = 1; d < 16; d <<= 1) m2 = fmaxf(m2, __shfl_xor(m2, d));
      float e2[4], s2 = 0.f;
#pragma unroll
      for (int n = 0; n < 4; ++n) { e2[n] = __expf(l2[n] - m2); s2 += e2[n]; }
#pragma unroll
      for (int d = 1; d < 16; d <<= 1) s2 += __shfl_xor(s2, d);
      float inv2 = 1.0f / s2;
#pragma unroll
      for (int n = 0; n < 4; ++n) outU[(size_t)rowg * 64 + s_ep + 16 * n] = e2[n] * inv2;

      if (s_ep == 0) {
        outI[(size_t)rowg * 3 + 0] = (float)tc[0];
        outI[(size_t)rowg * 3 + 1] = (float)tc[1];
        outI[(size_t)rowg * 3 + 2] = (float)tc[2];
        float mg = fminf(tv[0] - tv[1], fminf(tv[1] - tv[2], tv[2] - tv[3]));
        if (mg < TAU && cap > 0) {
          int pos = atomicAdd(cnt, 1);
          if (pos < cap) list[pos] = rowg;
        }
      }
    }
    __syncthreads();
  }
}

// fp64 refinement of near-tie rows: recompute logits exactly, overwrite idx.
__global__ __launch_bounds__(256, 4) void router_refine(
    const float* __restrict__ feat, const float* __restrict__ W1,
    const float* __restrict__ b1, const float* __restrict__ W2,
    const float* __restrict__ b2, float* __restrict__ out,
    const int* __restrict__ cnt, const int* __restrict__ list, int cap)
{
  __shared__ float  fbuf[4][1024];
  __shared__ double hbuf[4][256];
  int n = *cnt; if (n > cap) n = cap;
  if (n <= 0) return;
  const int tid = threadIdx.x;
  const int wv = tid >> 6;
  const int l  = tid & 63;
  float* outI = out + (size_t)NROWS * 64;
#pragma unroll 1
  for (int base = blockIdx.x * 4; base < n; base += 4096) {
    int nrows = n - base; if (nrows > 4) nrows = 4;
    for (int rr = 0; rr < 4; ++rr) {
      if (rr < nrows) {
        int row = list[base + rr];
        for (int i = tid; i < 1024; i += 256) fbuf[rr][i] = feat[(size_t)row * 1024 + i];
      }
    }
    __syncthreads();
    if (wv < nrows) {
      double zq0 = 0, zq1 = 0, zq2 = 0, zq3 = 0;
#pragma unroll 4
      for (int i = 0; i < 1024; ++i) {
        double f = (double)fbuf[wv][i];
        const float* wrow = W1 + (size_t)i * 256 + l;
        zq0 += f * (double)wrow[0];
        zq1 += f * (double)wrow[64];
        zq2 += f * (double)wrow[128];
        zq3 += f * (double)wrow[192];
      }
      double zz[4] = {zq0 + (double)b1[l],       zq1 + (double)b1[l + 64],
                      zq2 + (double)b1[l + 128], zq3 + (double)b1[l + 192]};
#pragma unroll
      for (int q = 0; q < 4; ++q) {
        double z = zz[q];
        hbuf[wv][l + 64 * q] = 0.5 * z * (1.0 + erf(z * 0.70710678118654752440));
      }
    }
    __syncthreads();
    if (wv < nrows) {
      double lgt = (double)b2[l];
#pragma unroll 4
      for (int j = 0; j < 256; ++j) lgt += hbuf[wv][j] * (double)W2[(size_t)j * 64 + l];
      int chosen[3];
      double curv = lgt;
      for (int t = 0; t < 3; ++t) {
        double mv = curv; int mc = l;
        for (int d = 1; d < 64; d <<= 1) {
          double ov = __shfl_xor(mv, d);
          int   oc = __shfl_xor(mc, d);
          if (ov > mv || (ov == mv && oc < mc)) { mv = ov; mc = oc; }
        }
        chosen[t] = mc;
        if (l == mc) curv = -1.0e300;
      }
      if (l == 0) {
        int row = list[base + wv];
        outI[(size_t)row * 3 + 0] = (float)chosen[0];
        outI[(size_t)row * 3 + 1] = (float)chosen[1];
        outI[(size_t)row * 3 + 2] = (float)chosen[2];
      }
    }
    __syncthreads();
  }
}

extern "C" void kernel_launch(void* const* d_in, const int* in_sizes, int n_in,
                              void* d_out, int out_size, void* d_ws, size_t ws_size,
                              hipStream_t stream) {
  (void)in_sizes; (void)n_in; (void)out_size;
  const float* feat = (const float*)d_in[0];
  const float* W1   = (const float*)d_in[1];
  const float* b1   = (const float*)d_in[2];
  const float* W2   = (const float*)d_in[3];
  const float* b2   = (const float*)d_in[4];
  float* out = (float*)d_out;

  size_t need_fused = (size_t)W1S_BYTES + 4 + 16384;
  size_t need_split = (size_t)W1S_BYTES + H_BYTES + 4 + 16384;

  if (ws_size >= need_split) {
    unsigned char* w1s = (unsigned char*)d_ws;
    float* hbuf = (float*)(w1s + W1S_BYTES);
    int* cnt  = (int*)((unsigned char*)d_ws + W1S_BYTES + H_BYTES);
    int* list = cnt + 1;
    long capl = (long)((ws_size - W1S_BYTES - H_BYTES - 4) / 4);
    int cap = capl > 65536 ? 65536 : (int)capl;
    hipLaunchKernelGGL(router_prep, dim3(128), dim3(256), 0, stream, W1, w1s, cnt);
    hipLaunchKernelGGL(router_gemm1, dim3(NROWS / BM1), dim3(1024), 0, stream,
                       feat, w1s, b1, hbuf);
    hipLaunchKernelGGL(router_gemm2, dim3(NROWS / 64), dim3(512), 0, stream,
                       hbuf, W2, b2, out, cnt, list, cap);
    hipLaunchKernelGGL(router_refine, dim3(1024), dim3(256), 0, stream,
                       feat, W1, b1, W2, b2, out, cnt, list, cap);
  } else if (ws_size >= need_fused) {
    unsigned char* w1s = (unsigned char*)d_ws;
    int* cnt  = (int*)(w1s + W1S_BYTES);
    int* list = cnt + 1;
    long capl = (long)((ws_size - W1S_BYTES - 4) / 4);
    int cap = capl > 65536 ? 65536 : (int)capl;
    hipLaunchKernelGGL(router_prep, dim3(128), dim3(256), 0, stream, W1, w1s, cnt);
    hipLaunchKernelGGL(router_fused, dim3(NROWS / 128), dim3(512), 0, stream,
                       feat, w1s, b1, W2, b2, out, cnt, list, cap);
    hipLaunchKernelGGL(router_refine, dim3(1024), dim3(256), 0, stream,
                       feat, W1, b1, W2, b2, out, cnt, list, cap);
  } else {
    int* cnt  = (int*)d_ws;
    int* list = cnt + 1;
    long capl = (ws_size >= 8) ? (long)(ws_size / 4) - 1 : 0;
    int cap = capl < 0 ? 0 : (capl > 65536 ? 65536 : (int)capl);
    if (cap > 0) hipMemsetAsync(cnt, 0, sizeof(int), stream);
    hipLaunchKernelGGL(router_main_legacy, dim3(NROWS / 128), dim3(512), 0, stream,
                       feat, W1, b1, W2, b2, out, cnt, list, cap);
    if (cap > 0)
      hipLaunchKernelGGL(router_refine, dim3(1024), dim3(256), 0, stream,
                         feat, W1, b1, W2, b2, out, cnt, list, cap);
  }
}